// Round 1
// baseline (2356.078 us; speedup 1.0000x reference)
//
#include <hip/hip_runtime.h>
#include <hip/hip_bf16.h>

#define NNODES 10000
#define NEDGE_IN 320000
#define ETOT (NEDGE_IN + NNODES)
#define FDIM 256

// ---------------- CSR build (dst-grouped incoming edge lists) ----------------
__global__ void count_deg_kernel(const int* __restrict__ ei, int* __restrict__ counts) {
  int e = blockIdx.x * blockDim.x + threadIdx.x;
  if (e >= ETOT) return;
  int d = (e < NEDGE_IN) ? ei[NEDGE_IN + e] : (e - NEDGE_IN);
  atomicAdd(&counts[d], 1);
}

__global__ void scan_kernel(const int* __restrict__ counts, int* __restrict__ row_ptr,
                            int* __restrict__ fill) {
  __shared__ int lds[256];
  __shared__ int carry;
  int t = threadIdx.x;
  if (t == 0) carry = 0;
  __syncthreads();
  for (int base = 0; base < NNODES; base += 256) {
    int i = base + t;
    int v = (i < NNODES) ? counts[i] : 0;
    lds[t] = v;
    __syncthreads();
    for (int off = 1; off < 256; off <<= 1) {
      int add = (t >= off) ? lds[t - off] : 0;
      __syncthreads();
      lds[t] += add;
      __syncthreads();
    }
    int excl = lds[t] - v;
    if (i < NNODES) { row_ptr[i] = carry + excl; fill[i] = carry + excl; }
    __syncthreads();
    if (t == 255) carry += lds[255];
    __syncthreads();
  }
  if (t == 0) row_ptr[NNODES] = carry;
}

__global__ void scatter_kernel(const int* __restrict__ ei, int* __restrict__ fill,
                               int* __restrict__ col_idx) {
  int e = blockIdx.x * blockDim.x + threadIdx.x;
  if (e >= ETOT) return;
  int s, d;
  if (e < NEDGE_IN) { s = ei[e]; d = ei[NEDGE_IN + e]; } else { s = d = e - NEDGE_IN; }
  int pos = atomicAdd(&fill[d], 1);
  col_idx[pos] = s;
}

// ---------------- fp32 GEMM: H[N,1024] = X[N,256] @ W[256,1024] ----------------
__global__ __launch_bounds__(256) void gemm_xw_kernel(const float* __restrict__ X,
                                                      const float* __restrict__ W,
                                                      float* __restrict__ H) {
  __shared__ float As[16][68];
  __shared__ float Bs[16][68];
  int t = threadIdx.x;
  int row0 = blockIdx.y * 64;
  int col0 = blockIdx.x * 64;
  int tx = t & 15, ty = t >> 4;
  float acc[4][4] = {};
  for (int k0 = 0; k0 < FDIM; k0 += 16) {
    int lk = t & 15, li = t >> 4;
#pragma unroll
    for (int ii = 0; ii < 4; ii++) {
      int i = li + 16 * ii;
      int r = row0 + i;
      As[lk][i] = (r < NNODES) ? X[(size_t)r * FDIM + k0 + lk] : 0.f;
    }
    int lj = t & 63, lk0 = t >> 6;
#pragma unroll
    for (int kk = 0; kk < 4; kk++) {
      int k = lk0 + 4 * kk;
      Bs[k][lj] = W[(size_t)(k0 + k) * 1024 + col0 + lj];
    }
    __syncthreads();
#pragma unroll
    for (int k = 0; k < 16; k++) {
      float4 a = *reinterpret_cast<const float4*>(&As[k][4 * ty]);
      float4 b = *reinterpret_cast<const float4*>(&Bs[k][4 * tx]);
      float av[4] = {a.x, a.y, a.z, a.w};
      float bv[4] = {b.x, b.y, b.z, b.w};
#pragma unroll
      for (int ii = 0; ii < 4; ii++)
#pragma unroll
        for (int jj = 0; jj < 4; jj++)
          acc[ii][jj] += av[ii] * bv[jj];
    }
    __syncthreads();
  }
#pragma unroll
  for (int ii = 0; ii < 4; ii++) {
    int r = row0 + 4 * ty + ii;
    if (r < NNODES) {
      float4 o = make_float4(acc[ii][0], acc[ii][1], acc[ii][2], acc[ii][3]);
      *reinterpret_cast<float4*>(&H[(size_t)r * 1024 + col0 + 4 * tx]) = o;
    }
  }
}

// ---------------- attention coefficients: al_s/al_d [N,4] ----------------
__global__ __launch_bounds__(256) void compute_al_kernel(const float* __restrict__ H,
                                                         const float* __restrict__ a_src,
                                                         const float* __restrict__ a_dst,
                                                         float* __restrict__ al_s,
                                                         float* __restrict__ al_d) {
  int n = blockIdx.x, t = threadIdx.x;
  float ps[4], pd[4];
#pragma unroll
  for (int hd = 0; hd < 4; hd++) {
    float v = H[(size_t)n * 1024 + hd * 256 + t];
    ps[hd] = v * a_src[hd * 256 + t];
    pd[hd] = v * a_dst[hd * 256 + t];
  }
  __shared__ float red[8][4];
  int lane = t & 63, wv = t >> 6;
#pragma unroll
  for (int q = 0; q < 8; q++) {
    float v = (q < 4) ? ps[q] : pd[q - 4];
#pragma unroll
    for (int off = 32; off > 0; off >>= 1) v += __shfl_down(v, off, 64);
    if (lane == 0) red[q][wv] = v;
  }
  __syncthreads();
  if (t < 8) {
    float v = red[t][0] + red[t][1] + red[t][2] + red[t][3];
    if (t < 4) al_s[n * 4 + t] = v;
    else al_d[n * 4 + (t - 4)] = v;
  }
}

// ---------------- per-dst softmax + aggregation + head-mean + bias + act ----------------
__global__ __launch_bounds__(256) void gat_aggregate_kernel(
    const float* __restrict__ H, const float* __restrict__ al_s, const float* __restrict__ al_d,
    const int* __restrict__ row_ptr, const int* __restrict__ col_idx,
    const float* __restrict__ bias, float* __restrict__ out, int act_tanh) {
  int n = blockIdx.x, t = threadIdx.x;
  int start = row_ptr[n], end = row_ptr[n + 1];
  float ald[4];
#pragma unroll
  for (int hd = 0; hd < 4; hd++) ald[hd] = al_d[n * 4 + hd];

  __shared__ float red[4][4];
  __shared__ float mS[4], invS[4];
  int lane = t & 63, wv = t >> 6;

  // Phase A: per-head max of leaky-relu logits
  float pm[4] = {-1e30f, -1e30f, -1e30f, -1e30f};
  for (int e = start + t; e < end; e += 256) {
    int s = col_idx[e];
#pragma unroll
    for (int hd = 0; hd < 4; hd++) {
      float l = al_s[s * 4 + hd] + ald[hd];
      l = (l > 0.f) ? l : 0.2f * l;
      pm[hd] = fmaxf(pm[hd], l);
    }
  }
#pragma unroll
  for (int hd = 0; hd < 4; hd++) {
    float v = pm[hd];
#pragma unroll
    for (int off = 32; off > 0; off >>= 1) v = fmaxf(v, __shfl_down(v, off, 64));
    if (lane == 0) red[hd][wv] = v;
  }
  __syncthreads();
  if (t < 4) mS[t] = fmaxf(fmaxf(red[t][0], red[t][1]), fmaxf(red[t][2], red[t][3]));
  __syncthreads();

  // Phase B: sum of exp
  float psum[4] = {0.f, 0.f, 0.f, 0.f};
  for (int e = start + t; e < end; e += 256) {
    int s = col_idx[e];
#pragma unroll
    for (int hd = 0; hd < 4; hd++) {
      float l = al_s[s * 4 + hd] + ald[hd];
      l = (l > 0.f) ? l : 0.2f * l;
      psum[hd] += expf(l - mS[hd]);
    }
  }
#pragma unroll
  for (int hd = 0; hd < 4; hd++) {
    float v = psum[hd];
#pragma unroll
    for (int off = 32; off > 0; off >>= 1) v += __shfl_down(v, off, 64);
    if (lane == 0) red[hd][wv] = v;
  }
  __syncthreads();
  if (t < 4) invS[t] = 1.f / (red[t][0] + red[t][1] + red[t][2] + red[t][3] + 1e-16f);
  __syncthreads();

  // Phase C: weighted aggregation; thread t owns feature t of each head
  __shared__ float alph[64][4];
  __shared__ int srcs[64];
  float acc0 = 0.f, acc1 = 0.f, acc2 = 0.f, acc3 = 0.f;
  for (int c = start; c < end; c += 64) {
    int nch = min(64, end - c);
    if (t < nch) {
      int s = col_idx[c + t];
      srcs[t] = s;
#pragma unroll
      for (int hd = 0; hd < 4; hd++) {
        float l = al_s[s * 4 + hd] + ald[hd];
        l = (l > 0.f) ? l : 0.2f * l;
        alph[t][hd] = expf(l - mS[hd]) * invS[hd];
      }
    }
    __syncthreads();
    for (int i = 0; i < nch; i++) {
      const float* hp = H + (size_t)srcs[i] * 1024 + t;
      acc0 += hp[0]   * alph[i][0];
      acc1 += hp[256] * alph[i][1];
      acc2 += hp[512] * alph[i][2];
      acc3 += hp[768] * alph[i][3];
    }
    __syncthreads();
  }
  float v = (acc0 + acc1 + acc2 + acc3) * 0.25f + bias[t];
  v = act_tanh ? tanhf(v) : fmaxf(v, 0.f);
  out[(size_t)n * 256 + t] = v;
}

// ---------------- adj = sigmoid(Z @ Z^T), [N,N] ----------------
__global__ __launch_bounds__(256) void zzt_kernel(const float* __restrict__ Z,
                                                  float* __restrict__ out) {
  __shared__ float As[16][68];
  __shared__ float Bs[16][68];
  int t = threadIdx.x;
  int row0 = blockIdx.y * 64;
  int col0 = blockIdx.x * 64;
  int tx = t & 15, ty = t >> 4;
  float acc[4][4] = {};
  for (int k0 = 0; k0 < FDIM; k0 += 16) {
    int lk = t & 15, li = t >> 4;
#pragma unroll
    for (int ii = 0; ii < 4; ii++) {
      int i = li + 16 * ii;
      int r = row0 + i, c = col0 + i;
      As[lk][i] = (r < NNODES) ? Z[(size_t)r * FDIM + k0 + lk] : 0.f;
      Bs[lk][i] = (c < NNODES) ? Z[(size_t)c * FDIM + k0 + lk] : 0.f;
    }
    __syncthreads();
#pragma unroll
    for (int k = 0; k < 16; k++) {
      float4 a = *reinterpret_cast<const float4*>(&As[k][4 * ty]);
      float4 b = *reinterpret_cast<const float4*>(&Bs[k][4 * tx]);
      float av[4] = {a.x, a.y, a.z, a.w};
      float bv[4] = {b.x, b.y, b.z, b.w};
#pragma unroll
      for (int ii = 0; ii < 4; ii++)
#pragma unroll
        for (int jj = 0; jj < 4; jj++)
          acc[ii][jj] += av[ii] * bv[jj];
    }
    __syncthreads();
  }
#pragma unroll
  for (int ii = 0; ii < 4; ii++) {
    int r = row0 + 4 * ty + ii;
    if (r >= NNODES) continue;
    int c0 = col0 + 4 * tx;
    float4 o;
    o.x = 1.f / (1.f + expf(-acc[ii][0]));
    o.y = 1.f / (1.f + expf(-acc[ii][1]));
    o.z = 1.f / (1.f + expf(-acc[ii][2]));
    o.w = 1.f / (1.f + expf(-acc[ii][3]));
    if (c0 + 3 < NNODES) {
      *reinterpret_cast<float4*>(&out[(size_t)r * NNODES + c0]) = o;
    } else {
      float ov[4] = {o.x, o.y, o.z, o.w};
      for (int jj = 0; jj < 4; jj++)
        if (c0 + jj < NNODES) out[(size_t)r * NNODES + c0 + jj] = ov[jj];
    }
  }
}

extern "C" void kernel_launch(void* const* d_in, const int* in_sizes, int n_in,
                              void* d_out, int out_size, void* d_ws, size_t ws_size,
                              hipStream_t stream) {
  const float* x = (const float*)d_in[0];
  const int* ei = (const int*)d_in[1];
  const float* W[4]  = {(const float*)d_in[2], (const float*)d_in[6], (const float*)d_in[10], (const float*)d_in[14]};
  const float* as[4] = {(const float*)d_in[3], (const float*)d_in[7], (const float*)d_in[11], (const float*)d_in[15]};
  const float* ad[4] = {(const float*)d_in[4], (const float*)d_in[8], (const float*)d_in[12], (const float*)d_in[16]};
  const float* bs[4] = {(const float*)d_in[5], (const float*)d_in[9], (const float*)d_in[13], (const float*)d_in[17]};

  char* ws = (char*)d_ws;
  size_t off = 0;
  auto alloc = [&](size_t bytes) -> void* {
    void* p = ws + off;
    off = (off + bytes + 255) & ~(size_t)255;
    return p;
  };
  float* h     = (float*)alloc(sizeof(float) * (size_t)NNODES * 1024);
  float* xA    = (float*)alloc(sizeof(float) * (size_t)NNODES * FDIM);
  float* xB    = (float*)alloc(sizeof(float) * (size_t)NNODES * FDIM);
  float* al_s  = (float*)alloc(sizeof(float) * NNODES * 4);
  float* al_d  = (float*)alloc(sizeof(float) * NNODES * 4);
  int* counts  = (int*)alloc(sizeof(int) * NNODES);
  int* row_ptr = (int*)alloc(sizeof(int) * (NNODES + 1));
  int* fill    = (int*)alloc(sizeof(int) * NNODES);
  int* col_idx = (int*)alloc(sizeof(int) * ETOT);

  hipMemsetAsync(counts, 0, sizeof(int) * NNODES, stream);
  int eblocks = (ETOT + 255) / 256;
  count_deg_kernel<<<eblocks, 256, 0, stream>>>(ei, counts);
  scan_kernel<<<1, 256, 0, stream>>>(counts, row_ptr, fill);
  scatter_kernel<<<eblocks, 256, 0, stream>>>(ei, fill, col_idx);

  float* z = (float*)d_out + (size_t)NNODES * NNODES;
  const float* xin = x;
  float* outs[4] = {xA, xB, xA, z};
  for (int l = 0; l < 4; l++) {
    gemm_xw_kernel<<<dim3(16, (NNODES + 63) / 64), 256, 0, stream>>>(xin, W[l], h);
    compute_al_kernel<<<NNODES, 256, 0, stream>>>(h, as[l], ad[l], al_s, al_d);
    gat_aggregate_kernel<<<NNODES, 256, 0, stream>>>(h, al_s, al_d, row_ptr, col_idx,
                                                     bs[l], outs[l], l == 3 ? 1 : 0);
    xin = outs[l];
  }
  zzt_kernel<<<dim3((NNODES + 63) / 64, (NNODES + 63) / 64), 256, 0, stream>>>(z, (float*)d_out);
}

// Round 2
// 1770.602 us; speedup vs baseline: 1.3307x; 1.3307x over previous
//
#include <hip/hip_runtime.h>
#include <hip/hip_bf16.h>

#define NNODES 10000
#define NEDGE_IN 320000
#define ETOT (NEDGE_IN + NNODES)
#define FDIM 256

typedef float floatx4 __attribute__((ext_vector_type(4)));
typedef __bf16 bf16x8 __attribute__((ext_vector_type(8)));

// ---------------- CSR build (dst-grouped incoming edge lists) ----------------
__global__ void count_deg_kernel(const int* __restrict__ ei, int* __restrict__ counts) {
  int e = blockIdx.x * blockDim.x + threadIdx.x;
  if (e >= ETOT) return;
  int d = (e < NEDGE_IN) ? ei[NEDGE_IN + e] : (e - NEDGE_IN);
  atomicAdd(&counts[d], 1);
}

__global__ void scan_kernel(const int* __restrict__ counts, int* __restrict__ row_ptr,
                            int* __restrict__ fill) {
  __shared__ int lds[256];
  __shared__ int carry;
  int t = threadIdx.x;
  if (t == 0) carry = 0;
  __syncthreads();
  for (int base = 0; base < NNODES; base += 256) {
    int i = base + t;
    int v = (i < NNODES) ? counts[i] : 0;
    lds[t] = v;
    __syncthreads();
    for (int off = 1; off < 256; off <<= 1) {
      int add = (t >= off) ? lds[t - off] : 0;
      __syncthreads();
      lds[t] += add;
      __syncthreads();
    }
    int excl = lds[t] - v;
    if (i < NNODES) { row_ptr[i] = carry + excl; fill[i] = carry + excl; }
    __syncthreads();
    if (t == 255) carry += lds[255];
    __syncthreads();
  }
  if (t == 0) row_ptr[NNODES] = carry;
}

__global__ void scatter_kernel(const int* __restrict__ ei, int* __restrict__ fill,
                               int* __restrict__ col_idx) {
  int e = blockIdx.x * blockDim.x + threadIdx.x;
  if (e >= ETOT) return;
  int s, d;
  if (e < NEDGE_IN) { s = ei[e]; d = ei[NEDGE_IN + e]; } else { s = d = e - NEDGE_IN; }
  int pos = atomicAdd(&fill[d], 1);
  col_idx[pos] = s;
}

// ---------------- fp32 GEMM: H[N,1024] = X[N,256] @ W[256,1024] ----------------
__global__ __launch_bounds__(256) void gemm_xw_kernel(const float* __restrict__ X,
                                                      const float* __restrict__ W,
                                                      float* __restrict__ H) {
  __shared__ float As[16][68];
  __shared__ float Bs[16][68];
  int t = threadIdx.x;
  int row0 = blockIdx.y * 64;
  int col0 = blockIdx.x * 64;
  int tx = t & 15, ty = t >> 4;
  float acc[4][4] = {};
  for (int k0 = 0; k0 < FDIM; k0 += 16) {
    int lk = t & 15, li = t >> 4;
#pragma unroll
    for (int ii = 0; ii < 4; ii++) {
      int i = li + 16 * ii;
      int r = row0 + i;
      As[lk][i] = (r < NNODES) ? X[(size_t)r * FDIM + k0 + lk] : 0.f;
    }
    int lj = t & 63, lk0 = t >> 6;
#pragma unroll
    for (int kk = 0; kk < 4; kk++) {
      int k = lk0 + 4 * kk;
      Bs[k][lj] = W[(size_t)(k0 + k) * 1024 + col0 + lj];
    }
    __syncthreads();
#pragma unroll
    for (int k = 0; k < 16; k++) {
      float4 a = *reinterpret_cast<const float4*>(&As[k][4 * ty]);
      float4 b = *reinterpret_cast<const float4*>(&Bs[k][4 * tx]);
      float av[4] = {a.x, a.y, a.z, a.w};
      float bv[4] = {b.x, b.y, b.z, b.w};
#pragma unroll
      for (int ii = 0; ii < 4; ii++)
#pragma unroll
        for (int jj = 0; jj < 4; jj++)
          acc[ii][jj] += av[ii] * bv[jj];
    }
    __syncthreads();
  }
#pragma unroll
  for (int ii = 0; ii < 4; ii++) {
    int r = row0 + 4 * ty + ii;
    if (r < NNODES) {
      float4 o = make_float4(acc[ii][0], acc[ii][1], acc[ii][2], acc[ii][3]);
      *reinterpret_cast<float4*>(&H[(size_t)r * 1024 + col0 + 4 * tx]) = o;
    }
  }
}

// ---------------- attention coefficients: al_s/al_d [N,4] ----------------
__global__ __launch_bounds__(256) void compute_al_kernel(const float* __restrict__ H,
                                                         const float* __restrict__ a_src,
                                                         const float* __restrict__ a_dst,
                                                         float* __restrict__ al_s,
                                                         float* __restrict__ al_d) {
  int n = blockIdx.x, t = threadIdx.x;
  float ps[4], pd[4];
#pragma unroll
  for (int hd = 0; hd < 4; hd++) {
    float v = H[(size_t)n * 1024 + hd * 256 + t];
    ps[hd] = v * a_src[hd * 256 + t];
    pd[hd] = v * a_dst[hd * 256 + t];
  }
  __shared__ float red[8][4];
  int lane = t & 63, wv = t >> 6;
#pragma unroll
  for (int q = 0; q < 8; q++) {
    float v = (q < 4) ? ps[q] : pd[q - 4];
#pragma unroll
    for (int off = 32; off > 0; off >>= 1) v += __shfl_down(v, off, 64);
    if (lane == 0) red[q][wv] = v;
  }
  __syncthreads();
  if (t < 8) {
    float v = red[t][0] + red[t][1] + red[t][2] + red[t][3];
    if (t < 4) al_s[n * 4 + t] = v;
    else al_d[n * 4 + (t - 4)] = v;
  }
}

// ---------------- per-dst softmax + aggregation + head-mean + bias + act ----------------
__global__ __launch_bounds__(256) void gat_aggregate_kernel(
    const float* __restrict__ H, const float* __restrict__ al_s, const float* __restrict__ al_d,
    const int* __restrict__ row_ptr, const int* __restrict__ col_idx,
    const float* __restrict__ bias, float* __restrict__ out, int act_tanh) {
  int n = blockIdx.x, t = threadIdx.x;
  int start = row_ptr[n], end = row_ptr[n + 1];
  float ald[4];
#pragma unroll
  for (int hd = 0; hd < 4; hd++) ald[hd] = al_d[n * 4 + hd];

  __shared__ float red[4][4];
  __shared__ float mS[4], invS[4];
  int lane = t & 63, wv = t >> 6;

  float pm[4] = {-1e30f, -1e30f, -1e30f, -1e30f};
  for (int e = start + t; e < end; e += 256) {
    int s = col_idx[e];
#pragma unroll
    for (int hd = 0; hd < 4; hd++) {
      float l = al_s[s * 4 + hd] + ald[hd];
      l = (l > 0.f) ? l : 0.2f * l;
      pm[hd] = fmaxf(pm[hd], l);
    }
  }
#pragma unroll
  for (int hd = 0; hd < 4; hd++) {
    float v = pm[hd];
#pragma unroll
    for (int off = 32; off > 0; off >>= 1) v = fmaxf(v, __shfl_down(v, off, 64));
    if (lane == 0) red[hd][wv] = v;
  }
  __syncthreads();
  if (t < 4) mS[t] = fmaxf(fmaxf(red[t][0], red[t][1]), fmaxf(red[t][2], red[t][3]));
  __syncthreads();

  float psum[4] = {0.f, 0.f, 0.f, 0.f};
  for (int e = start + t; e < end; e += 256) {
    int s = col_idx[e];
#pragma unroll
    for (int hd = 0; hd < 4; hd++) {
      float l = al_s[s * 4 + hd] + ald[hd];
      l = (l > 0.f) ? l : 0.2f * l;
      psum[hd] += expf(l - mS[hd]);
    }
  }
#pragma unroll
  for (int hd = 0; hd < 4; hd++) {
    float v = psum[hd];
#pragma unroll
    for (int off = 32; off > 0; off >>= 1) v += __shfl_down(v, off, 64);
    if (lane == 0) red[hd][wv] = v;
  }
  __syncthreads();
  if (t < 4) invS[t] = 1.f / (red[t][0] + red[t][1] + red[t][2] + red[t][3] + 1e-16f);
  __syncthreads();

  __shared__ float alph[64][4];
  __shared__ int srcs[64];
  float acc0 = 0.f, acc1 = 0.f, acc2 = 0.f, acc3 = 0.f;
  for (int c = start; c < end; c += 64) {
    int nch = min(64, end - c);
    if (t < nch) {
      int s = col_idx[c + t];
      srcs[t] = s;
#pragma unroll
      for (int hd = 0; hd < 4; hd++) {
        float l = al_s[s * 4 + hd] + ald[hd];
        l = (l > 0.f) ? l : 0.2f * l;
        alph[t][hd] = expf(l - mS[hd]) * invS[hd];
      }
    }
    __syncthreads();
    for (int i = 0; i < nch; i++) {
      const float* hp = H + (size_t)srcs[i] * 1024 + t;
      acc0 += hp[0]   * alph[i][0];
      acc1 += hp[256] * alph[i][1];
      acc2 += hp[512] * alph[i][2];
      acc3 += hp[768] * alph[i][3];
    }
    __syncthreads();
  }
  float v = (acc0 + acc1 + acc2 + acc3) * 0.25f + bias[t];
  v = act_tanh ? tanhf(v) : fmaxf(v, 0.f);
  out[(size_t)n * 256 + t] = v;
}

// ---------------- split z (fp32) into hi/lo bf16 (truncation split) ----------------
__global__ __launch_bounds__(256) void split_bf16_kernel(const float* __restrict__ z,
                                                         unsigned short* __restrict__ hi,
                                                         unsigned short* __restrict__ lo) {
  int i = blockIdx.x * 256 + threadIdx.x;
  if (i >= NNODES * FDIM) return;
  float v = z[i];
  unsigned u = __float_as_uint(v);
  unsigned hu = u & 0xffff0000u;
  float r = v - __uint_as_float(hu);
  hi[i] = (unsigned short)(u >> 16);
  lo[i] = (unsigned short)(__float_as_uint(r) >> 16);
}

// ---------------- adj = sigmoid(Z @ Z^T) via bf16 MFMA, 3-term split ----------------
// 128x128 tile, BK=64, XOR-swizzled LDS (chunk ^= row&7) so frag ds_read_b128
// is <=2-way conflicted while remaining global_load_lds-compatible.
#define AHI_OFF 0
#define ALO_OFF 16384
#define BHI_OFF 32768
#define BLO_OFF 49152

__global__ __launch_bounds__(256, 2) void zzt_mfma_kernel(
    const unsigned short* __restrict__ zhi, const unsigned short* __restrict__ zlo,
    float* __restrict__ out) {
  __shared__ __align__(16) char lds[65536];
  int t = threadIdx.x;
  int lane = t & 63, wv = t >> 6;
  int quad = lane >> 4, lr = lane & 15;
  int row0 = blockIdx.y * 128;
  int col0 = blockIdx.x * 128;
  int wm = (wv & 1) * 64, wn = (wv >> 1) * 64;

  floatx4 acc[4][4];
#pragma unroll
  for (int i = 0; i < 4; i++)
#pragma unroll
    for (int j = 0; j < 4; j++) acc[i][j] = (floatx4){0.f, 0.f, 0.f, 0.f};

  for (int ks = 0; ks < 4; ks++) {
    // stage 4 tiles of 16 KB each (128 rows x 128 B) via global_load_lds
#pragma unroll
    for (int mat = 0; mat < 4; mat++) {
      const unsigned short* src = (mat == 0 || mat == 2) ? zhi : zlo;
      int rowbase = (mat < 2) ? row0 : col0;
      int ldsoff = mat * 16384;
#pragma unroll
      for (int it = 0; it < 4; it++) {
        int lin = ((wv * 4 + it) << 10) + lane * 16;  // byte offset in tile
        int R = lin >> 7;                              // tile row 0..127
        int c = (lin >> 4) & 7;                        // physical 16B chunk
        int g = c ^ (R & 7);                           // logical k-chunk
        int gr = rowbase + R;
        if (gr > NNODES - 1) gr = NNODES - 1;
        const char* gp = (const char*)src + (size_t)gr * 512 + ks * 128 + g * 16;
        __builtin_amdgcn_global_load_lds(
            (const __attribute__((address_space(1))) void*)gp,
            (__attribute__((address_space(3))) void*)(lds + ldsoff + lin), 16, 0, 0);
      }
    }
    __syncthreads();

#pragma unroll
    for (int ksub = 0; ksub < 2; ksub++) {
      int g = ksub * 4 + quad;
      bf16x8 ah[4], al_[4], bh[4], bl[4];
#pragma unroll
      for (int mi = 0; mi < 4; mi++) {
        int m = wm + mi * 16 + lr;
        int off = m * 128 + ((g ^ (m & 7)) << 4);
        ah[mi] = *(const bf16x8*)(lds + AHI_OFF + off);
        al_[mi] = *(const bf16x8*)(lds + ALO_OFF + off);
      }
#pragma unroll
      for (int ni = 0; ni < 4; ni++) {
        int n = wn + ni * 16 + lr;
        int off = n * 128 + ((g ^ (n & 7)) << 4);
        bh[ni] = *(const bf16x8*)(lds + BHI_OFF + off);
        bl[ni] = *(const bf16x8*)(lds + BLO_OFF + off);
      }
#pragma unroll
      for (int mi = 0; mi < 4; mi++)
#pragma unroll
        for (int ni = 0; ni < 4; ni++) {
          acc[mi][ni] = __builtin_amdgcn_mfma_f32_16x16x32_bf16(ah[mi], bh[ni], acc[mi][ni], 0, 0, 0);
          acc[mi][ni] = __builtin_amdgcn_mfma_f32_16x16x32_bf16(ah[mi], bl[ni], acc[mi][ni], 0, 0, 0);
          acc[mi][ni] = __builtin_amdgcn_mfma_f32_16x16x32_bf16(al_[mi], bh[ni], acc[mi][ni], 0, 0, 0);
        }
    }
    __syncthreads();
  }

  // epilogue: sigmoid + store. C layout: col=lane&15, row=quad*4+reg
#pragma unroll
  for (int mi = 0; mi < 4; mi++) {
#pragma unroll
    for (int ni = 0; ni < 4; ni++) {
      int col = col0 + wn + ni * 16 + lr;
      if (col >= NNODES) continue;
#pragma unroll
      for (int r = 0; r < 4; r++) {
        int row = row0 + wm + mi * 16 + quad * 4 + r;
        if (row < NNODES) {
          float v = acc[mi][ni][r];
          out[(size_t)row * NNODES + col] = 1.f / (1.f + __expf(-v));
        }
      }
    }
  }
}

extern "C" void kernel_launch(void* const* d_in, const int* in_sizes, int n_in,
                              void* d_out, int out_size, void* d_ws, size_t ws_size,
                              hipStream_t stream) {
  const float* x = (const float*)d_in[0];
  const int* ei = (const int*)d_in[1];
  const float* W[4]  = {(const float*)d_in[2], (const float*)d_in[6], (const float*)d_in[10], (const float*)d_in[14]};
  const float* as[4] = {(const float*)d_in[3], (const float*)d_in[7], (const float*)d_in[11], (const float*)d_in[15]};
  const float* ad[4] = {(const float*)d_in[4], (const float*)d_in[8], (const float*)d_in[12], (const float*)d_in[16]};
  const float* bs[4] = {(const float*)d_in[5], (const float*)d_in[9], (const float*)d_in[13], (const float*)d_in[17]};

  char* ws = (char*)d_ws;
  size_t off = 0;
  auto alloc = [&](size_t bytes) -> void* {
    void* p = ws + off;
    off = (off + bytes + 255) & ~(size_t)255;
    return p;
  };
  float* h     = (float*)alloc(sizeof(float) * (size_t)NNODES * 1024);
  float* xA    = (float*)alloc(sizeof(float) * (size_t)NNODES * FDIM);
  float* xB    = (float*)alloc(sizeof(float) * (size_t)NNODES * FDIM);
  float* al_s  = (float*)alloc(sizeof(float) * NNODES * 4);
  float* al_d  = (float*)alloc(sizeof(float) * NNODES * 4);
  int* counts  = (int*)alloc(sizeof(int) * NNODES);
  int* row_ptr = (int*)alloc(sizeof(int) * (NNODES + 1));
  int* fill    = (int*)alloc(sizeof(int) * NNODES);
  int* col_idx = (int*)alloc(sizeof(int) * ETOT);
  unsigned short* zhi = (unsigned short*)alloc(sizeof(unsigned short) * (size_t)NNODES * FDIM);
  unsigned short* zlo = (unsigned short*)alloc(sizeof(unsigned short) * (size_t)NNODES * FDIM);

  hipMemsetAsync(counts, 0, sizeof(int) * NNODES, stream);
  int eblocks = (ETOT + 255) / 256;
  count_deg_kernel<<<eblocks, 256, 0, stream>>>(ei, counts);
  scan_kernel<<<1, 256, 0, stream>>>(counts, row_ptr, fill);
  scatter_kernel<<<eblocks, 256, 0, stream>>>(ei, fill, col_idx);

  float* z = (float*)d_out + (size_t)NNODES * NNODES;
  const float* xin = x;
  float* outs[4] = {xA, xB, xA, z};
  for (int l = 0; l < 4; l++) {
    gemm_xw_kernel<<<dim3(16, (NNODES + 63) / 64), 256, 0, stream>>>(xin, W[l], h);
    compute_al_kernel<<<NNODES, 256, 0, stream>>>(h, as[l], ad[l], al_s, al_d);
    gat_aggregate_kernel<<<NNODES, 256, 0, stream>>>(h, al_s, al_d, row_ptr, col_idx,
                                                     bs[l], outs[l], l == 3 ? 1 : 0);
    xin = outs[l];
  }
  split_bf16_kernel<<<(NNODES * FDIM + 255) / 256, 256, 0, stream>>>(z, zhi, zlo);
  zzt_mfma_kernel<<<dim3(79, 79), 256, 0, stream>>>(zhi, zlo, (float*)d_out);
}

// Round 3
// 1246.365 us; speedup vs baseline: 1.8904x; 1.4206x over previous
//
#include <hip/hip_runtime.h>
#include <hip/hip_bf16.h>

#define NNODES 10000
#define NEDGE_IN 320000
#define ETOT (NEDGE_IN + NNODES)
#define FDIM 256

typedef float floatx4 __attribute__((ext_vector_type(4)));
typedef __bf16 bf16x8 __attribute__((ext_vector_type(8)));

__device__ __forceinline__ float bf2f(unsigned short u) {
  return __uint_as_float((unsigned)u << 16);
}
__device__ __forceinline__ unsigned short f2bf_rn(float v) {
  unsigned u = __float_as_uint(v);
  return (unsigned short)((u + 0x7fffu + ((u >> 16) & 1u)) >> 16);
}

// ---------------- CSR build (dst-grouped incoming edge lists) ----------------
__global__ void count_deg_kernel(const int* __restrict__ ei, int* __restrict__ counts) {
  int e = blockIdx.x * blockDim.x + threadIdx.x;
  if (e >= ETOT) return;
  int d = (e < NEDGE_IN) ? ei[NEDGE_IN + e] : (e - NEDGE_IN);
  atomicAdd(&counts[d], 1);
}

__global__ void scan_kernel(const int* __restrict__ counts, int* __restrict__ row_ptr,
                            int* __restrict__ fill) {
  __shared__ int lds[256];
  __shared__ int carry;
  int t = threadIdx.x;
  if (t == 0) carry = 0;
  __syncthreads();
  for (int base = 0; base < NNODES; base += 256) {
    int i = base + t;
    int v = (i < NNODES) ? counts[i] : 0;
    lds[t] = v;
    __syncthreads();
    for (int off = 1; off < 256; off <<= 1) {
      int add = (t >= off) ? lds[t - off] : 0;
      __syncthreads();
      lds[t] += add;
      __syncthreads();
    }
    int excl = lds[t] - v;
    if (i < NNODES) { row_ptr[i] = carry + excl; fill[i] = carry + excl; }
    __syncthreads();
    if (t == 255) carry += lds[255];
    __syncthreads();
  }
  if (t == 0) row_ptr[NNODES] = carry;
}

__global__ void scatter_kernel(const int* __restrict__ ei, int* __restrict__ fill,
                               int* __restrict__ col_idx) {
  int e = blockIdx.x * blockDim.x + threadIdx.x;
  if (e >= ETOT) return;
  int s, d;
  if (e < NEDGE_IN) { s = ei[e]; d = ei[NEDGE_IN + e]; } else { s = d = e - NEDGE_IN; }
  int pos = atomicAdd(&fill[d], 1);
  col_idx[pos] = s;
}

// ---------------- split fp32 -> hi/lo bf16 (truncation split) ----------------
__global__ __launch_bounds__(256) void split_bf16_kernel(const float* __restrict__ z,
                                                         unsigned short* __restrict__ hi,
                                                         unsigned short* __restrict__ lo) {
  int i = blockIdx.x * 256 + threadIdx.x;
  if (i >= NNODES * FDIM) return;
  float v = z[i];
  unsigned u = __float_as_uint(v);
  unsigned hu = u & 0xffff0000u;
  float r = v - __uint_as_float(hu);
  hi[i] = (unsigned short)(u >> 16);
  lo[i] = (unsigned short)(__float_as_uint(r) >> 16);
}

// ---------------- W prep: transpose+split W[256,1024] -> WT hi/lo [1024,256] ----------------
__global__ __launch_bounds__(256) void prep_w_kernel(const float* __restrict__ W,
                                                     unsigned short* __restrict__ whiT,
                                                     unsigned short* __restrict__ wloT) {
  __shared__ float tile[32][33];
  int t = threadIdx.x;
  int tx = t & 31, ty = t >> 5;  // ty 0..7
  int n0 = blockIdx.x * 32, k0 = blockIdx.y * 32;
#pragma unroll
  for (int i = 0; i < 4; i++) {
    int kr = ty + 8 * i;
    tile[kr][tx] = W[(size_t)(k0 + kr) * 1024 + n0 + tx];
  }
  __syncthreads();
#pragma unroll
  for (int i = 0; i < 4; i++) {
    int nr = ty + 8 * i;
    float v = tile[tx][nr];  // W[k0+tx][n0+nr]
    unsigned u = __float_as_uint(v);
    float r = v - __uint_as_float(u & 0xffff0000u);
    size_t o = (size_t)(n0 + nr) * 256 + k0 + tx;
    whiT[o] = (unsigned short)(u >> 16);
    wloT[o] = (unsigned short)(__float_as_uint(r) >> 16);
  }
}

// ---------------- Wa prep: Was/Wad[k,h] = sum_f W[k, h*256+f] * a[h,f] ----------------
__global__ __launch_bounds__(256) void prep_wa_kernel(const float* __restrict__ W,
                                                      const float* __restrict__ a_src,
                                                      const float* __restrict__ a_dst,
                                                      float* __restrict__ Was,
                                                      float* __restrict__ Wad) {
  int k = blockIdx.x, t = threadIdx.x;
  float ps[4], pd[4];
#pragma unroll
  for (int hd = 0; hd < 4; hd++) {
    float w = W[(size_t)k * 1024 + hd * 256 + t];
    ps[hd] = w * a_src[hd * 256 + t];
    pd[hd] = w * a_dst[hd * 256 + t];
  }
  __shared__ float red[8][4];
  int lane = t & 63, wv = t >> 6;
#pragma unroll
  for (int q = 0; q < 8; q++) {
    float v = (q < 4) ? ps[q] : pd[q - 4];
#pragma unroll
    for (int off = 32; off > 0; off >>= 1) v += __shfl_down(v, off, 64);
    if (lane == 0) red[q][wv] = v;
  }
  __syncthreads();
  if (t < 8) {
    float v = red[t][0] + red[t][1] + red[t][2] + red[t][3];
    if (t < 4) Was[k * 4 + t] = v;
    else Wad[k * 4 + (t - 4)] = v;
  }
}

// ---------------- al_s/al_d[n,h] = X[n,:] @ Was/Wad ----------------
__global__ __launch_bounds__(256) void al_kernel(const float* __restrict__ X,
                                                 const float* __restrict__ Was,
                                                 const float* __restrict__ Wad,
                                                 float* __restrict__ al_s,
                                                 float* __restrict__ al_d) {
  int n = blockIdx.x, t = threadIdx.x;
  float x = X[(size_t)n * 256 + t];
  float4 ws = *reinterpret_cast<const float4*>(Was + t * 4);
  float4 wd = *reinterpret_cast<const float4*>(Wad + t * 4);
  float ps[4] = {x * ws.x, x * ws.y, x * ws.z, x * ws.w};
  float pd[4] = {x * wd.x, x * wd.y, x * wd.z, x * wd.w};
  __shared__ float red[8][4];
  int lane = t & 63, wv = t >> 6;
#pragma unroll
  for (int q = 0; q < 8; q++) {
    float v = (q < 4) ? ps[q] : pd[q - 4];
#pragma unroll
    for (int off = 32; off > 0; off >>= 1) v += __shfl_down(v, off, 64);
    if (lane == 0) red[q][wv] = v;
  }
  __syncthreads();
  if (t < 8) {
    float v = red[t][0] + red[t][1] + red[t][2] + red[t][3];
    if (t < 4) al_s[n * 4 + t] = v;
    else al_d[n * 4 + (t - 4)] = v;
  }
}

// ---------------- MFMA GEMM: Hb[10000,1024] (bf16) = X @ W, 3-term split ----------------
#define AHI_OFF 0
#define ALO_OFF 16384
#define BHI_OFF 32768
#define BLO_OFF 49152

__global__ __launch_bounds__(256, 2) void gemm_mfma_kernel(
    const unsigned short* __restrict__ xhi, const unsigned short* __restrict__ xlo,
    const unsigned short* __restrict__ whiT, const unsigned short* __restrict__ wloT,
    unsigned short* __restrict__ Hb) {
  __shared__ __align__(16) char lds[65536];
  int t = threadIdx.x;
  int lane = t & 63, wv = t >> 6;
  int quad = lane >> 4, lr = lane & 15;
  int row0 = blockIdx.y * 128;
  int col0 = blockIdx.x * 128;
  int wm = (wv & 1) * 64, wn = (wv >> 1) * 64;

  floatx4 acc[4][4];
#pragma unroll
  for (int i = 0; i < 4; i++)
#pragma unroll
    for (int j = 0; j < 4; j++) acc[i][j] = (floatx4){0.f, 0.f, 0.f, 0.f};

  for (int ks = 0; ks < 4; ks++) {
#pragma unroll
    for (int mat = 0; mat < 4; mat++) {
      const unsigned short* src = (mat == 0) ? xhi : (mat == 1) ? xlo : (mat == 2) ? whiT : wloT;
      int rowbase = (mat < 2) ? row0 : col0;
      int maxrow = (mat < 2) ? (NNODES - 1) : 1023;
      int ldsoff = mat * 16384;
#pragma unroll
      for (int it = 0; it < 4; it++) {
        int lin = ((wv * 4 + it) << 10) + lane * 16;
        int R = lin >> 7;
        int c = (lin >> 4) & 7;
        int g = c ^ (R & 7);
        int gr = rowbase + R;
        if (gr > maxrow) gr = maxrow;
        const char* gp = (const char*)src + (size_t)gr * 512 + ks * 128 + g * 16;
        __builtin_amdgcn_global_load_lds(
            (const __attribute__((address_space(1))) void*)gp,
            (__attribute__((address_space(3))) void*)(lds + ldsoff + lin), 16, 0, 0);
      }
    }
    __syncthreads();

#pragma unroll
    for (int ksub = 0; ksub < 2; ksub++) {
      int g = ksub * 4 + quad;
      bf16x8 ah[4], al_[4], bh[4], bl[4];
#pragma unroll
      for (int mi = 0; mi < 4; mi++) {
        int m = wm + mi * 16 + lr;
        int off = m * 128 + ((g ^ (m & 7)) << 4);
        ah[mi] = *(const bf16x8*)(lds + AHI_OFF + off);
        al_[mi] = *(const bf16x8*)(lds + ALO_OFF + off);
      }
#pragma unroll
      for (int ni = 0; ni < 4; ni++) {
        int n = wn + ni * 16 + lr;
        int off = n * 128 + ((g ^ (n & 7)) << 4);
        bh[ni] = *(const bf16x8*)(lds + BHI_OFF + off);
        bl[ni] = *(const bf16x8*)(lds + BLO_OFF + off);
      }
#pragma unroll
      for (int mi = 0; mi < 4; mi++)
#pragma unroll
        for (int ni = 0; ni < 4; ni++) {
          acc[mi][ni] = __builtin_amdgcn_mfma_f32_16x16x32_bf16(ah[mi], bh[ni], acc[mi][ni], 0, 0, 0);
          acc[mi][ni] = __builtin_amdgcn_mfma_f32_16x16x32_bf16(ah[mi], bl[ni], acc[mi][ni], 0, 0, 0);
          acc[mi][ni] = __builtin_amdgcn_mfma_f32_16x16x32_bf16(al_[mi], bh[ni], acc[mi][ni], 0, 0, 0);
        }
    }
    __syncthreads();
  }

#pragma unroll
  for (int mi = 0; mi < 4; mi++) {
#pragma unroll
    for (int ni = 0; ni < 4; ni++) {
      int col = col0 + wn + ni * 16 + lr;
#pragma unroll
      for (int r = 0; r < 4; r++) {
        int row = row0 + wm + mi * 16 + quad * 4 + r;
        if (row < NNODES) Hb[(size_t)row * 1024 + col] = f2bf_rn(acc[mi][ni][r]);
      }
    }
  }
}

// ---------------- per-dst softmax + bf16 aggregation + head-mean + bias + act + split ----------------
__global__ __launch_bounds__(256) void gat_aggregate_kernel(
    const unsigned short* __restrict__ Hb, const float* __restrict__ al_s,
    const float* __restrict__ al_d, const int* __restrict__ row_ptr,
    const int* __restrict__ col_idx, const float* __restrict__ bias,
    float* __restrict__ outF, unsigned short* __restrict__ outHi,
    unsigned short* __restrict__ outLo, int act_tanh) {
  int n = blockIdx.x, t = threadIdx.x;
  int start = row_ptr[n], end = row_ptr[n + 1];
  float ald[4];
#pragma unroll
  for (int hd = 0; hd < 4; hd++) ald[hd] = al_d[n * 4 + hd];

  __shared__ float red[4][4];
  __shared__ float mS[4], invS[4];
  int lane = t & 63, wv = t >> 6;

  // Phase A: per-head max of leaky-relu logits
  float pm[4] = {-1e30f, -1e30f, -1e30f, -1e30f};
  for (int e = start + t; e < end; e += 256) {
    int s = col_idx[e];
    float4 as4 = *reinterpret_cast<const float4*>(al_s + s * 4);
    float av[4] = {as4.x, as4.y, as4.z, as4.w};
#pragma unroll
    for (int hd = 0; hd < 4; hd++) {
      float l = av[hd] + ald[hd];
      l = (l > 0.f) ? l : 0.2f * l;
      pm[hd] = fmaxf(pm[hd], l);
    }
  }
#pragma unroll
  for (int hd = 0; hd < 4; hd++) {
    float v = pm[hd];
#pragma unroll
    for (int off = 32; off > 0; off >>= 1) v = fmaxf(v, __shfl_down(v, off, 64));
    if (lane == 0) red[hd][wv] = v;
  }
  __syncthreads();
  if (t < 4) mS[t] = fmaxf(fmaxf(red[t][0], red[t][1]), fmaxf(red[t][2], red[t][3]));
  __syncthreads();

  // Phase B: sum of exp
  float psum[4] = {0.f, 0.f, 0.f, 0.f};
  for (int e = start + t; e < end; e += 256) {
    int s = col_idx[e];
    float4 as4 = *reinterpret_cast<const float4*>(al_s + s * 4);
    float av[4] = {as4.x, as4.y, as4.z, as4.w};
#pragma unroll
    for (int hd = 0; hd < 4; hd++) {
      float l = av[hd] + ald[hd];
      l = (l > 0.f) ? l : 0.2f * l;
      psum[hd] += __expf(l - mS[hd]);
    }
  }
#pragma unroll
  for (int hd = 0; hd < 4; hd++) {
    float v = psum[hd];
#pragma unroll
    for (int off = 32; off > 0; off >>= 1) v += __shfl_down(v, off, 64);
    if (lane == 0) red[hd][wv] = v;
  }
  __syncthreads();
  if (t < 4) invS[t] = 1.f / (red[t][0] + red[t][1] + red[t][2] + red[t][3] + 1e-16f);
  __syncthreads();

  // Phase C: wave wv owns head wv; thread owns 4 consecutive features
  __shared__ float alph[64][4];
  __shared__ int srcs[64];
  int hd = t >> 6;
  int f0 = (t & 63) * 4;
  float a0 = 0.f, a1 = 0.f, a2 = 0.f, a3 = 0.f;
  for (int c = start; c < end; c += 64) {
    int nch = min(64, end - c);
    if (t < nch) {
      int s = col_idx[c + t];
      srcs[t] = s;
      float4 as4 = *reinterpret_cast<const float4*>(al_s + s * 4);
      float av[4] = {as4.x, as4.y, as4.z, as4.w};
#pragma unroll
      for (int h2 = 0; h2 < 4; h2++) {
        float l = av[h2] + ald[h2];
        l = (l > 0.f) ? l : 0.2f * l;
        alph[t][h2] = __expf(l - mS[h2]) * invS[h2];
      }
    }
    __syncthreads();
    for (int i = 0; i < nch; i++) {
      const ushort4 v = *reinterpret_cast<const ushort4*>(Hb + (size_t)srcs[i] * 1024 + hd * 256 + f0);
      float al = alph[i][hd];
      a0 += bf2f(v.x) * al;
      a1 += bf2f(v.y) * al;
      a2 += bf2f(v.z) * al;
      a3 += bf2f(v.w) * al;
    }
    __syncthreads();
  }

  __shared__ float shf[4][256];
  *reinterpret_cast<float4*>(&shf[hd][f0]) = make_float4(a0, a1, a2, a3);
  __syncthreads();
  if (t < 64) {
    int f = t * 4;
    float4 o;
    float ov[4];
#pragma unroll
    for (int j = 0; j < 4; j++) {
      float s = shf[0][f + j] + shf[1][f + j] + shf[2][f + j] + shf[3][f + j];
      float v = s * 0.25f + bias[f + j];
      v = act_tanh ? tanhf(v) : fmaxf(v, 0.f);
      ov[j] = v;
    }
    o = make_float4(ov[0], ov[1], ov[2], ov[3]);
    *reinterpret_cast<float4*>(outF + (size_t)n * 256 + f) = o;
    ushort4 hv, lv;
    unsigned u0 = __float_as_uint(ov[0]), u1 = __float_as_uint(ov[1]);
    unsigned u2 = __float_as_uint(ov[2]), u3 = __float_as_uint(ov[3]);
    hv.x = (unsigned short)(u0 >> 16); hv.y = (unsigned short)(u1 >> 16);
    hv.z = (unsigned short)(u2 >> 16); hv.w = (unsigned short)(u3 >> 16);
    lv.x = (unsigned short)(__float_as_uint(ov[0] - __uint_as_float(u0 & 0xffff0000u)) >> 16);
    lv.y = (unsigned short)(__float_as_uint(ov[1] - __uint_as_float(u1 & 0xffff0000u)) >> 16);
    lv.z = (unsigned short)(__float_as_uint(ov[2] - __uint_as_float(u2 & 0xffff0000u)) >> 16);
    lv.w = (unsigned short)(__float_as_uint(ov[3] - __uint_as_float(u3 & 0xffff0000u)) >> 16);
    *reinterpret_cast<ushort4*>(outHi + (size_t)n * 256 + f) = hv;
    *reinterpret_cast<ushort4*>(outLo + (size_t)n * 256 + f) = lv;
  }
}

// ---------------- adj = sigmoid(Z @ Z^T) via bf16 MFMA, 3-term split ----------------
__global__ __launch_bounds__(256, 2) void zzt_mfma_kernel(
    const unsigned short* __restrict__ zhi, const unsigned short* __restrict__ zlo,
    float* __restrict__ out) {
  __shared__ __align__(16) char lds[65536];
  int t = threadIdx.x;
  int lane = t & 63, wv = t >> 6;
  int quad = lane >> 4, lr = lane & 15;
  int row0 = blockIdx.y * 128;
  int col0 = blockIdx.x * 128;
  int wm = (wv & 1) * 64, wn = (wv >> 1) * 64;

  floatx4 acc[4][4];
#pragma unroll
  for (int i = 0; i < 4; i++)
#pragma unroll
    for (int j = 0; j < 4; j++) acc[i][j] = (floatx4){0.f, 0.f, 0.f, 0.f};

  for (int ks = 0; ks < 4; ks++) {
#pragma unroll
    for (int mat = 0; mat < 4; mat++) {
      const unsigned short* src = (mat == 0 || mat == 2) ? zhi : zlo;
      int rowbase = (mat < 2) ? row0 : col0;
      int ldsoff = mat * 16384;
#pragma unroll
      for (int it = 0; it < 4; it++) {
        int lin = ((wv * 4 + it) << 10) + lane * 16;
        int R = lin >> 7;
        int c = (lin >> 4) & 7;
        int g = c ^ (R & 7);
        int gr = rowbase + R;
        if (gr > NNODES - 1) gr = NNODES - 1;
        const char* gp = (const char*)src + (size_t)gr * 512 + ks * 128 + g * 16;
        __builtin_amdgcn_global_load_lds(
            (const __attribute__((address_space(1))) void*)gp,
            (__attribute__((address_space(3))) void*)(lds + ldsoff + lin), 16, 0, 0);
      }
    }
    __syncthreads();

#pragma unroll
    for (int ksub = 0; ksub < 2; ksub++) {
      int g = ksub * 4 + quad;
      bf16x8 ah[4], al_[4], bh[4], bl[4];
#pragma unroll
      for (int mi = 0; mi < 4; mi++) {
        int m = wm + mi * 16 + lr;
        int off = m * 128 + ((g ^ (m & 7)) << 4);
        ah[mi] = *(const bf16x8*)(lds + AHI_OFF + off);
        al_[mi] = *(const bf16x8*)(lds + ALO_OFF + off);
      }
#pragma unroll
      for (int ni = 0; ni < 4; ni++) {
        int n = wn + ni * 16 + lr;
        int off = n * 128 + ((g ^ (n & 7)) << 4);
        bh[ni] = *(const bf16x8*)(lds + BHI_OFF + off);
        bl[ni] = *(const bf16x8*)(lds + BLO_OFF + off);
      }
#pragma unroll
      for (int mi = 0; mi < 4; mi++)
#pragma unroll
        for (int ni = 0; ni < 4; ni++) {
          acc[mi][ni] = __builtin_amdgcn_mfma_f32_16x16x32_bf16(ah[mi], bh[ni], acc[mi][ni], 0, 0, 0);
          acc[mi][ni] = __builtin_amdgcn_mfma_f32_16x16x32_bf16(ah[mi], bl[ni], acc[mi][ni], 0, 0, 0);
          acc[mi][ni] = __builtin_amdgcn_mfma_f32_16x16x32_bf16(al_[mi], bh[ni], acc[mi][ni], 0, 0, 0);
        }
    }
    __syncthreads();
  }

#pragma unroll
  for (int mi = 0; mi < 4; mi++) {
#pragma unroll
    for (int ni = 0; ni < 4; ni++) {
      int col = col0 + wn + ni * 16 + lr;
      if (col >= NNODES) continue;
#pragma unroll
      for (int r = 0; r < 4; r++) {
        int row = row0 + wm + mi * 16 + quad * 4 + r;
        if (row < NNODES) {
          float v = acc[mi][ni][r];
          out[(size_t)row * NNODES + col] = 1.f / (1.f + __expf(-v));
        }
      }
    }
  }
}

extern "C" void kernel_launch(void* const* d_in, const int* in_sizes, int n_in,
                              void* d_out, int out_size, void* d_ws, size_t ws_size,
                              hipStream_t stream) {
  const float* x = (const float*)d_in[0];
  const int* ei = (const int*)d_in[1];
  const float* W[4]  = {(const float*)d_in[2], (const float*)d_in[6], (const float*)d_in[10], (const float*)d_in[14]};
  const float* as[4] = {(const float*)d_in[3], (const float*)d_in[7], (const float*)d_in[11], (const float*)d_in[15]};
  const float* ad[4] = {(const float*)d_in[4], (const float*)d_in[8], (const float*)d_in[12], (const float*)d_in[16]};
  const float* bs[4] = {(const float*)d_in[5], (const float*)d_in[9], (const float*)d_in[13], (const float*)d_in[17]};

  char* ws = (char*)d_ws;
  size_t off = 0;
  auto alloc = [&](size_t bytes) -> void* {
    void* p = ws + off;
    off = (off + bytes + 255) & ~(size_t)255;
    return p;
  };
  unsigned short* Hb  = (unsigned short*)alloc(sizeof(unsigned short) * (size_t)NNODES * 1024);
  unsigned short* shi = (unsigned short*)alloc(sizeof(unsigned short) * (size_t)NNODES * FDIM);
  unsigned short* slo = (unsigned short*)alloc(sizeof(unsigned short) * (size_t)NNODES * FDIM);
  unsigned short* whiT = (unsigned short*)alloc(sizeof(unsigned short) * 1024 * 256);
  unsigned short* wloT = (unsigned short*)alloc(sizeof(unsigned short) * 1024 * 256);
  float* xA    = (float*)alloc(sizeof(float) * (size_t)NNODES * FDIM);
  float* xB    = (float*)alloc(sizeof(float) * (size_t)NNODES * FDIM);
  float* al_s  = (float*)alloc(sizeof(float) * NNODES * 4);
  float* al_d  = (float*)alloc(sizeof(float) * NNODES * 4);
  float* Was   = (float*)alloc(sizeof(float) * 256 * 4);
  float* Wad   = (float*)alloc(sizeof(float) * 256 * 4);
  int* counts  = (int*)alloc(sizeof(int) * NNODES);
  int* row_ptr = (int*)alloc(sizeof(int) * (NNODES + 1));
  int* fill    = (int*)alloc(sizeof(int) * NNODES);
  int* col_idx = (int*)alloc(sizeof(int) * ETOT);

  hipMemsetAsync(counts, 0, sizeof(int) * NNODES, stream);
  int eblocks = (ETOT + 255) / 256;
  count_deg_kernel<<<eblocks, 256, 0, stream>>>(ei, counts);
  scan_kernel<<<1, 256, 0, stream>>>(counts, row_ptr, fill);
  scatter_kernel<<<eblocks, 256, 0, stream>>>(ei, fill, col_idx);
  split_bf16_kernel<<<(NNODES * FDIM + 255) / 256, 256, 0, stream>>>(x, shi, slo);

  float* z = (float*)d_out + (size_t)NNODES * NNODES;
  const float* xin = x;
  float* outs[4] = {xA, xB, xA, z};
  for (int l = 0; l < 4; l++) {
    prep_w_kernel<<<dim3(32, 8), 256, 0, stream>>>(W[l], whiT, wloT);
    prep_wa_kernel<<<256, 256, 0, stream>>>(W[l], as[l], ad[l], Was, Wad);
    gemm_mfma_kernel<<<dim3(8, 79), 256, 0, stream>>>(shi, slo, whiT, wloT, Hb);
    al_kernel<<<NNODES, 256, 0, stream>>>(xin, Was, Wad, al_s, al_d);
    gat_aggregate_kernel<<<NNODES, 256, 0, stream>>>(Hb, al_s, al_d, row_ptr, col_idx,
                                                     bs[l], outs[l], shi, slo, l == 3 ? 1 : 0);
    xin = outs[l];
  }
  zzt_mfma_kernel<<<dim3(79, 79), 256, 0, stream>>>(shi, slo, (float*)d_out);
}

// Round 4
// 1199.340 us; speedup vs baseline: 1.9645x; 1.0392x over previous
//
#include <hip/hip_runtime.h>
#include <hip/hip_bf16.h>

#define NNODES 10000
#define NEDGE_IN 320000
#define ETOT (NEDGE_IN + NNODES)
#define FDIM 256

typedef float floatx4 __attribute__((ext_vector_type(4)));
typedef __bf16 bf16x8 __attribute__((ext_vector_type(8)));

__device__ __forceinline__ float bf2f(unsigned short u) {
  return __uint_as_float((unsigned)u << 16);
}

// ---------------- CSR build (dst-grouped incoming edge lists) ----------------
__global__ void count_deg_kernel(const int* __restrict__ ei, int* __restrict__ counts) {
  int e = blockIdx.x * blockDim.x + threadIdx.x;
  if (e >= ETOT) return;
  int d = (e < NEDGE_IN) ? ei[NEDGE_IN + e] : (e - NEDGE_IN);
  atomicAdd(&counts[d], 1);
}

// 256 threads, 40 contiguous counts per thread; ~20 barriers total.
__global__ __launch_bounds__(256) void scan_kernel(const int* __restrict__ counts,
                                                   int* __restrict__ row_ptr,
                                                   int* __restrict__ fill) {
  int t = threadIdx.x;
  const int CH = 40;
  int base = t * CH;
  int local[CH];
  int sum = 0;
#pragma unroll
  for (int i = 0; i < CH; i++) {
    int idx = base + i;
    int v = (idx < NNODES) ? counts[idx] : 0;
    local[i] = sum;
    sum += v;
  }
  __shared__ int ssum[256];
  ssum[t] = sum;
  __syncthreads();
  for (int off = 1; off < 256; off <<= 1) {
    int add = (t >= off) ? ssum[t - off] : 0;
    __syncthreads();
    ssum[t] += add;
    __syncthreads();
  }
  int excl = ssum[t] - sum;
#pragma unroll
  for (int i = 0; i < CH; i++) {
    int idx = base + i;
    if (idx < NNODES) {
      int v = excl + local[i];
      row_ptr[idx] = v;
      fill[idx] = v;
    }
  }
  if (t == 255) row_ptr[NNODES] = ssum[255];
}

__global__ void scatter_kernel(const int* __restrict__ ei, int* __restrict__ fill,
                               int* __restrict__ col_idx) {
  int e = blockIdx.x * blockDim.x + threadIdx.x;
  if (e >= ETOT) return;
  int s, d;
  if (e < NEDGE_IN) { s = ei[e]; d = ei[NEDGE_IN + e]; } else { s = d = e - NEDGE_IN; }
  int pos = atomicAdd(&fill[d], 1);
  col_idx[pos] = s;
}

// ---------------- split fp32 -> hi/lo bf16 (truncation split) ----------------
__global__ __launch_bounds__(256) void split_bf16_kernel(const float* __restrict__ z,
                                                         unsigned short* __restrict__ hi,
                                                         unsigned short* __restrict__ lo) {
  int i = blockIdx.x * 256 + threadIdx.x;
  if (i >= NNODES * FDIM) return;
  float v = z[i];
  unsigned u = __float_as_uint(v);
  unsigned hu = u & 0xffff0000u;
  float r = v - __uint_as_float(hu);
  hi[i] = (unsigned short)(u >> 16);
  lo[i] = (unsigned short)(__float_as_uint(r) >> 16);
}

// ---------------- BT prep: BT[f, h*256+k] = 0.25*W[k, h*256+f], split hi/lo ----------------
__global__ __launch_bounds__(256) void prep_bt_kernel(const float* __restrict__ W,
                                                      unsigned short* __restrict__ btHi,
                                                      unsigned short* __restrict__ btLo) {
  __shared__ float tile[32][33];
  int t = threadIdx.x;
  int tx = t & 31, ty = t >> 5;  // ty 0..7
  int f0 = blockIdx.x * 32, k0 = blockIdx.y * 32, h = blockIdx.z;
#pragma unroll
  for (int i = 0; i < 4; i++) {
    int kr = ty + 8 * i;
    tile[kr][tx] = W[(size_t)(k0 + kr) * 1024 + h * 256 + f0 + tx];
  }
  __syncthreads();
#pragma unroll
  for (int i = 0; i < 4; i++) {
    int fr = ty + 8 * i;
    float v = 0.25f * tile[tx][fr];  // 0.25*W[k0+tx][h*256+f0+fr]
    unsigned u = __float_as_uint(v);
    float r = v - __uint_as_float(u & 0xffff0000u);
    size_t o = (size_t)(f0 + fr) * 1024 + h * 256 + k0 + tx;
    btHi[o] = (unsigned short)(u >> 16);
    btLo[o] = (unsigned short)(__float_as_uint(r) >> 16);
  }
}

// ---------------- Wa prep: Was/Wad[k,h] = sum_f W[k, h*256+f] * a[h,f] ----------------
__global__ __launch_bounds__(256) void prep_wa_kernel(const float* __restrict__ W,
                                                      const float* __restrict__ a_src,
                                                      const float* __restrict__ a_dst,
                                                      float* __restrict__ Was,
                                                      float* __restrict__ Wad) {
  int k = blockIdx.x, t = threadIdx.x;
  float ps[4], pd[4];
#pragma unroll
  for (int hd = 0; hd < 4; hd++) {
    float w = W[(size_t)k * 1024 + hd * 256 + t];
    ps[hd] = w * a_src[hd * 256 + t];
    pd[hd] = w * a_dst[hd * 256 + t];
  }
  __shared__ float red[8][4];
  int lane = t & 63, wv = t >> 6;
#pragma unroll
  for (int q = 0; q < 8; q++) {
    float v = (q < 4) ? ps[q] : pd[q - 4];
#pragma unroll
    for (int off = 32; off > 0; off >>= 1) v += __shfl_down(v, off, 64);
    if (lane == 0) red[q][wv] = v;
  }
  __syncthreads();
  if (t < 8) {
    float v = red[t][0] + red[t][1] + red[t][2] + red[t][3];
    if (t < 4) Was[k * 4 + t] = v;
    else Wad[k * 4 + (t - 4)] = v;
  }
}

// ---------------- al_s/al_d[n,h] = X[n,:] @ Was/Wad ----------------
__global__ __launch_bounds__(256) void al_kernel(const float* __restrict__ X,
                                                 const float* __restrict__ Was,
                                                 const float* __restrict__ Wad,
                                                 float* __restrict__ al_s,
                                                 float* __restrict__ al_d) {
  int n = blockIdx.x, t = threadIdx.x;
  float x = X[(size_t)n * 256 + t];
  float4 ws = *reinterpret_cast<const float4*>(Was + t * 4);
  float4 wd = *reinterpret_cast<const float4*>(Wad + t * 4);
  float ps[4] = {x * ws.x, x * ws.y, x * ws.z, x * ws.w};
  float pd[4] = {x * wd.x, x * wd.y, x * wd.z, x * wd.w};
  __shared__ float red[8][4];
  int lane = t & 63, wv = t >> 6;
#pragma unroll
  for (int q = 0; q < 8; q++) {
    float v = (q < 4) ? ps[q] : pd[q - 4];
#pragma unroll
    for (int off = 32; off > 0; off >>= 1) v += __shfl_down(v, off, 64);
    if (lane == 0) red[q][wv] = v;
  }
  __syncthreads();
  if (t < 8) {
    float v = red[t][0] + red[t][1] + red[t][2] + red[t][3];
    if (t < 4) al_s[n * 4 + t] = v;
    else al_d[n * 4 + (t - 4)] = v;
  }
}

// ---------------- softmax + gather x (bf16-hi) -> xagg[N,4,256] hi/lo ----------------
__global__ __launch_bounds__(256) void gat_gather_kernel(
    const unsigned short* __restrict__ xhi, const float* __restrict__ al_s,
    const float* __restrict__ al_d, const int* __restrict__ row_ptr,
    const int* __restrict__ col_idx, float* __restrict__ llog,
    unsigned short* __restrict__ aggHi, unsigned short* __restrict__ aggLo) {
  int n = blockIdx.x, t = threadIdx.x;
  int start = row_ptr[n], end = row_ptr[n + 1];
  float ald[4];
#pragma unroll
  for (int hd = 0; hd < 4; hd++) ald[hd] = al_d[n * 4 + hd];

  __shared__ float red[4][4];
  __shared__ float mS[4], invS[4];
  int lane = t & 63, wv = t >> 6;

  // Phase A: logits -> llog (linear), track per-head max
  float pm[4] = {-1e30f, -1e30f, -1e30f, -1e30f};
  for (int e = start + t; e < end; e += 256) {
    int s = col_idx[e];
    float4 as4 = *reinterpret_cast<const float4*>(al_s + s * 4);
    float lv[4] = {as4.x + ald[0], as4.y + ald[1], as4.z + ald[2], as4.w + ald[3]};
#pragma unroll
    for (int hd = 0; hd < 4; hd++) {
      float l = lv[hd];
      l = (l > 0.f) ? l : 0.2f * l;
      lv[hd] = l;
      pm[hd] = fmaxf(pm[hd], l);
    }
    *reinterpret_cast<float4*>(llog + (size_t)e * 4) = make_float4(lv[0], lv[1], lv[2], lv[3]);
  }
#pragma unroll
  for (int hd = 0; hd < 4; hd++) {
    float v = pm[hd];
#pragma unroll
    for (int off = 32; off > 0; off >>= 1) v = fmaxf(v, __shfl_down(v, off, 64));
    if (lane == 0) red[hd][wv] = v;
  }
  __syncthreads();
  if (t < 4) mS[t] = fmaxf(fmaxf(red[t][0], red[t][1]), fmaxf(red[t][2], red[t][3]));
  __syncthreads();

  // Phase B: exp(l - m) -> llog, accumulate sum
  float psum[4] = {0.f, 0.f, 0.f, 0.f};
  for (int e = start + t; e < end; e += 256) {
    float4 l4 = *reinterpret_cast<const float4*>(llog + (size_t)e * 4);
    float ex[4] = {__expf(l4.x - mS[0]), __expf(l4.y - mS[1]),
                   __expf(l4.z - mS[2]), __expf(l4.w - mS[3])};
#pragma unroll
    for (int hd = 0; hd < 4; hd++) psum[hd] += ex[hd];
    *reinterpret_cast<float4*>(llog + (size_t)e * 4) = make_float4(ex[0], ex[1], ex[2], ex[3]);
  }
#pragma unroll
  for (int hd = 0; hd < 4; hd++) {
    float v = psum[hd];
#pragma unroll
    for (int off = 32; off > 0; off >>= 1) v += __shfl_down(v, off, 64);
    if (lane == 0) red[hd][wv] = v;
  }
  __syncthreads();
  if (t < 4) invS[t] = 1.f / (red[t][0] + red[t][1] + red[t][2] + red[t][3] + 1e-16f);
  __syncthreads();

  // Phase C: wave wv = head, thread covers 4 consecutive x-features
  __shared__ float alph[64][4];
  __shared__ int srcs[64];
  int hd = t >> 6;
  int fl = (t & 63) * 4;
  float a0 = 0.f, a1 = 0.f, a2 = 0.f, a3 = 0.f;
  for (int c = start; c < end; c += 64) {
    int nch = min(64, end - c);
    if (t < nch) {
      srcs[t] = col_idx[c + t];
      float4 ex = *reinterpret_cast<const float4*>(llog + (size_t)(c + t) * 4);
      alph[t][0] = ex.x * invS[0];
      alph[t][1] = ex.y * invS[1];
      alph[t][2] = ex.z * invS[2];
      alph[t][3] = ex.w * invS[3];
    }
    __syncthreads();
    for (int i = 0; i < nch; i++) {
      const ushort4 v = *reinterpret_cast<const ushort4*>(xhi + (size_t)srcs[i] * 256 + fl);
      float al = alph[i][hd];
      a0 += bf2f(v.x) * al;
      a1 += bf2f(v.y) * al;
      a2 += bf2f(v.z) * al;
      a3 += bf2f(v.w) * al;
    }
    __syncthreads();
  }
  // store xagg hi/lo (truncation split)
  float av[4] = {a0, a1, a2, a3};
  ushort4 hv, lv;
  unsigned short* hp = (unsigned short*)&hv;
  unsigned short* lp = (unsigned short*)&lv;
#pragma unroll
  for (int j = 0; j < 4; j++) {
    unsigned u = __float_as_uint(av[j]);
    float r = av[j] - __uint_as_float(u & 0xffff0000u);
    hp[j] = (unsigned short)(u >> 16);
    lp[j] = (unsigned short)(__float_as_uint(r) >> 16);
  }
  size_t o = (size_t)n * 1024 + hd * 256 + fl;
  *reinterpret_cast<ushort4*>(aggHi + o) = hv;
  *reinterpret_cast<ushort4*>(aggLo + o) = lv;
}

// ---------------- MFMA GEMM v2: out[N,256] = xagg[N,1024] @ BT^T + bias, act, split ----------------
#define AHI_OFF 0
#define ALO_OFF 16384
#define BHI_OFF 32768
#define BLO_OFF 49152

__global__ __launch_bounds__(256, 2) void gemm_out_kernel(
    const unsigned short* __restrict__ aggHi, const unsigned short* __restrict__ aggLo,
    const unsigned short* __restrict__ btHi, const unsigned short* __restrict__ btLo,
    const float* __restrict__ bias, float* __restrict__ outF,
    unsigned short* __restrict__ outHi, unsigned short* __restrict__ outLo, int act_tanh) {
  __shared__ __align__(16) char lds[65536];
  int t = threadIdx.x;
  int lane = t & 63, wv = t >> 6;
  int quad = lane >> 4, lr = lane & 15;
  int row0 = blockIdx.y * 128;
  int col0 = blockIdx.x * 128;
  int wm = (wv & 1) * 64, wn = (wv >> 1) * 64;

  floatx4 acc[4][4];
#pragma unroll
  for (int i = 0; i < 4; i++)
#pragma unroll
    for (int j = 0; j < 4; j++) acc[i][j] = (floatx4){0.f, 0.f, 0.f, 0.f};

  for (int ks = 0; ks < 16; ks++) {
#pragma unroll
    for (int mat = 0; mat < 4; mat++) {
      const unsigned short* src = (mat == 0) ? aggHi : (mat == 1) ? aggLo : (mat == 2) ? btHi : btLo;
      int rowbase = (mat < 2) ? row0 : col0;
      int maxrow = (mat < 2) ? (NNODES - 1) : 255;
      int ldsoff = mat * 16384;
#pragma unroll
      for (int it = 0; it < 4; it++) {
        int lin = ((wv * 4 + it) << 10) + lane * 16;
        int R = lin >> 7;
        int c = (lin >> 4) & 7;
        int g = c ^ (R & 7);
        int gr = rowbase + R;
        if (gr > maxrow) gr = maxrow;
        const char* gp = (const char*)src + (size_t)gr * 2048 + ks * 128 + g * 16;
        __builtin_amdgcn_global_load_lds(
            (const __attribute__((address_space(1))) void*)gp,
            (__attribute__((address_space(3))) void*)(lds + ldsoff + lin), 16, 0, 0);
      }
    }
    __syncthreads();

#pragma unroll
    for (int ksub = 0; ksub < 2; ksub++) {
      int g = ksub * 4 + quad;
      bf16x8 ah[4], al_[4], bh[4], bl[4];
#pragma unroll
      for (int mi = 0; mi < 4; mi++) {
        int m = wm + mi * 16 + lr;
        int off = m * 128 + ((g ^ (m & 7)) << 4);
        ah[mi] = *(const bf16x8*)(lds + AHI_OFF + off);
        al_[mi] = *(const bf16x8*)(lds + ALO_OFF + off);
      }
#pragma unroll
      for (int ni = 0; ni < 4; ni++) {
        int n = wn + ni * 16 + lr;
        int off = n * 128 + ((g ^ (n & 7)) << 4);
        bh[ni] = *(const bf16x8*)(lds + BHI_OFF + off);
        bl[ni] = *(const bf16x8*)(lds + BLO_OFF + off);
      }
#pragma unroll
      for (int mi = 0; mi < 4; mi++)
#pragma unroll
        for (int ni = 0; ni < 4; ni++) {
          acc[mi][ni] = __builtin_amdgcn_mfma_f32_16x16x32_bf16(ah[mi], bh[ni], acc[mi][ni], 0, 0, 0);
          acc[mi][ni] = __builtin_amdgcn_mfma_f32_16x16x32_bf16(ah[mi], bl[ni], acc[mi][ni], 0, 0, 0);
          acc[mi][ni] = __builtin_amdgcn_mfma_f32_16x16x32_bf16(al_[mi], bh[ni], acc[mi][ni], 0, 0, 0);
        }
    }
    __syncthreads();
  }

#pragma unroll
  for (int mi = 0; mi < 4; mi++) {
#pragma unroll
    for (int ni = 0; ni < 4; ni++) {
      int col = col0 + wn + ni * 16 + lr;
      float bv = bias[col];
#pragma unroll
      for (int r = 0; r < 4; r++) {
        int row = row0 + wm + mi * 16 + quad * 4 + r;
        if (row < NNODES) {
          float v = acc[mi][ni][r] + bv;
          v = act_tanh ? tanhf(v) : fmaxf(v, 0.f);
          size_t o = (size_t)row * 256 + col;
          outF[o] = v;
          unsigned u = __float_as_uint(v);
          float rr = v - __uint_as_float(u & 0xffff0000u);
          outHi[o] = (unsigned short)(u >> 16);
          outLo[o] = (unsigned short)(__float_as_uint(rr) >> 16);
        }
      }
    }
  }
}

// ---------------- adj = sigmoid(Z @ Z^T) via bf16 MFMA, 3-term split ----------------
__global__ __launch_bounds__(256, 2) void zzt_mfma_kernel(
    const unsigned short* __restrict__ zhi, const unsigned short* __restrict__ zlo,
    float* __restrict__ out) {
  __shared__ __align__(16) char lds[65536];
  int t = threadIdx.x;
  int lane = t & 63, wv = t >> 6;
  int quad = lane >> 4, lr = lane & 15;
  int row0 = blockIdx.y * 128;
  int col0 = blockIdx.x * 128;
  int wm = (wv & 1) * 64, wn = (wv >> 1) * 64;

  floatx4 acc[4][4];
#pragma unroll
  for (int i = 0; i < 4; i++)
#pragma unroll
    for (int j = 0; j < 4; j++) acc[i][j] = (floatx4){0.f, 0.f, 0.f, 0.f};

  for (int ks = 0; ks < 4; ks++) {
#pragma unroll
    for (int mat = 0; mat < 4; mat++) {
      const unsigned short* src = (mat == 0 || mat == 2) ? zhi : zlo;
      int rowbase = (mat < 2) ? row0 : col0;
      int ldsoff = mat * 16384;
#pragma unroll
      for (int it = 0; it < 4; it++) {
        int lin = ((wv * 4 + it) << 10) + lane * 16;
        int R = lin >> 7;
        int c = (lin >> 4) & 7;
        int g = c ^ (R & 7);
        int gr = rowbase + R;
        if (gr > NNODES - 1) gr = NNODES - 1;
        const char* gp = (const char*)src + (size_t)gr * 512 + ks * 128 + g * 16;
        __builtin_amdgcn_global_load_lds(
            (const __attribute__((address_space(1))) void*)gp,
            (__attribute__((address_space(3))) void*)(lds + ldsoff + lin), 16, 0, 0);
      }
    }
    __syncthreads();

#pragma unroll
    for (int ksub = 0; ksub < 2; ksub++) {
      int g = ksub * 4 + quad;
      bf16x8 ah[4], al_[4], bh[4], bl[4];
#pragma unroll
      for (int mi = 0; mi < 4; mi++) {
        int m = wm + mi * 16 + lr;
        int off = m * 128 + ((g ^ (m & 7)) << 4);
        ah[mi] = *(const bf16x8*)(lds + AHI_OFF + off);
        al_[mi] = *(const bf16x8*)(lds + ALO_OFF + off);
      }
#pragma unroll
      for (int ni = 0; ni < 4; ni++) {
        int n = wn + ni * 16 + lr;
        int off = n * 128 + ((g ^ (n & 7)) << 4);
        bh[ni] = *(const bf16x8*)(lds + BHI_OFF + off);
        bl[ni] = *(const bf16x8*)(lds + BLO_OFF + off);
      }
#pragma unroll
      for (int mi = 0; mi < 4; mi++)
#pragma unroll
        for (int ni = 0; ni < 4; ni++) {
          acc[mi][ni] = __builtin_amdgcn_mfma_f32_16x16x32_bf16(ah[mi], bh[ni], acc[mi][ni], 0, 0, 0);
          acc[mi][ni] = __builtin_amdgcn_mfma_f32_16x16x32_bf16(ah[mi], bl[ni], acc[mi][ni], 0, 0, 0);
          acc[mi][ni] = __builtin_amdgcn_mfma_f32_16x16x32_bf16(al_[mi], bh[ni], acc[mi][ni], 0, 0, 0);
        }
    }
    __syncthreads();
  }

#pragma unroll
  for (int mi = 0; mi < 4; mi++) {
#pragma unroll
    for (int ni = 0; ni < 4; ni++) {
      int col = col0 + wn + ni * 16 + lr;
      if (col >= NNODES) continue;
#pragma unroll
      for (int r = 0; r < 4; r++) {
        int row = row0 + wm + mi * 16 + quad * 4 + r;
        if (row < NNODES) {
          float v = acc[mi][ni][r];
          out[(size_t)row * NNODES + col] = 1.f / (1.f + __expf(-v));
        }
      }
    }
  }
}

extern "C" void kernel_launch(void* const* d_in, const int* in_sizes, int n_in,
                              void* d_out, int out_size, void* d_ws, size_t ws_size,
                              hipStream_t stream) {
  const float* x = (const float*)d_in[0];
  const int* ei = (const int*)d_in[1];
  const float* W[4]  = {(const float*)d_in[2], (const float*)d_in[6], (const float*)d_in[10], (const float*)d_in[14]};
  const float* as[4] = {(const float*)d_in[3], (const float*)d_in[7], (const float*)d_in[11], (const float*)d_in[15]};
  const float* ad[4] = {(const float*)d_in[4], (const float*)d_in[8], (const float*)d_in[12], (const float*)d_in[16]};
  const float* bs[4] = {(const float*)d_in[5], (const float*)d_in[9], (const float*)d_in[13], (const float*)d_in[17]};

  char* ws = (char*)d_ws;
  size_t off = 0;
  auto alloc = [&](size_t bytes) -> void* {
    void* p = ws + off;
    off = (off + bytes + 255) & ~(size_t)255;
    return p;
  };
  unsigned short* aggHi = (unsigned short*)alloc(sizeof(unsigned short) * (size_t)NNODES * 1024);
  unsigned short* aggLo = (unsigned short*)alloc(sizeof(unsigned short) * (size_t)NNODES * 1024);
  unsigned short* shi   = (unsigned short*)alloc(sizeof(unsigned short) * (size_t)NNODES * FDIM);
  unsigned short* slo   = (unsigned short*)alloc(sizeof(unsigned short) * (size_t)NNODES * FDIM);
  unsigned short* btHi  = (unsigned short*)alloc(sizeof(unsigned short) * 256 * 1024);
  unsigned short* btLo  = (unsigned short*)alloc(sizeof(unsigned short) * 256 * 1024);
  float* xF    = (float*)alloc(sizeof(float) * (size_t)NNODES * FDIM);
  float* llog  = (float*)alloc(sizeof(float) * (size_t)ETOT * 4);
  float* al_s  = (float*)alloc(sizeof(float) * NNODES * 4);
  float* al_d  = (float*)alloc(sizeof(float) * NNODES * 4);
  float* Was   = (float*)alloc(sizeof(float) * 256 * 4);
  float* Wad   = (float*)alloc(sizeof(float) * 256 * 4);
  int* counts  = (int*)alloc(sizeof(int) * NNODES);
  int* row_ptr = (int*)alloc(sizeof(int) * (NNODES + 1));
  int* fill    = (int*)alloc(sizeof(int) * NNODES);
  int* col_idx = (int*)alloc(sizeof(int) * ETOT);

  hipMemsetAsync(counts, 0, sizeof(int) * NNODES, stream);
  int eblocks = (ETOT + 255) / 256;
  count_deg_kernel<<<eblocks, 256, 0, stream>>>(ei, counts);
  scan_kernel<<<1, 256, 0, stream>>>(counts, row_ptr, fill);
  scatter_kernel<<<eblocks, 256, 0, stream>>>(ei, fill, col_idx);
  split_bf16_kernel<<<(NNODES * FDIM + 255) / 256, 256, 0, stream>>>(x, shi, slo);

  float* z = (float*)d_out + (size_t)NNODES * NNODES;
  const float* xin = x;
  for (int l = 0; l < 4; l++) {
    prep_bt_kernel<<<dim3(8, 8, 4), 256, 0, stream>>>(W[l], btHi, btLo);
    prep_wa_kernel<<<256, 256, 0, stream>>>(W[l], as[l], ad[l], Was, Wad);
    al_kernel<<<NNODES, 256, 0, stream>>>(xin, Was, Wad, al_s, al_d);
    gat_gather_kernel<<<NNODES, 256, 0, stream>>>(shi, al_s, al_d, row_ptr, col_idx,
                                                  llog, aggHi, aggLo);
    float* outF = (l == 3) ? z : xF;
    gemm_out_kernel<<<dim3(2, 79), 256, 0, stream>>>(aggHi, aggLo, btHi, btLo, bs[l],
                                                     outF, shi, slo, l == 3 ? 1 : 0);
    xin = xF;
  }
  zzt_mfma_kernel<<<dim3(79, 79), 256, 0, stream>>>(shi, slo, (float*)d_out);
}

// Round 5
// 1060.932 us; speedup vs baseline: 2.2208x; 1.1305x over previous
//
#include <hip/hip_runtime.h>
#include <hip/hip_bf16.h>

#define NNODES 10000
#define NEDGE_IN 320000
#define ETOT (NEDGE_IN + NNODES)
#define FDIM 256
#define NT 79  // 128-tiles covering 10000

typedef float floatx4 __attribute__((ext_vector_type(4)));
typedef __bf16 bf16x8 __attribute__((ext_vector_type(8)));

__device__ __forceinline__ float bf2f(unsigned short u) {
  return __uint_as_float((unsigned)u << 16);
}

// ---------------- CSR build (dst-grouped incoming edge lists) ----------------
__global__ void count_deg_kernel(const int* __restrict__ ei, int* __restrict__ counts) {
  int e = blockIdx.x * blockDim.x + threadIdx.x;
  if (e >= ETOT) return;
  int d = (e < NEDGE_IN) ? ei[NEDGE_IN + e] : (e - NEDGE_IN);
  atomicAdd(&counts[d], 1);
}

__global__ __launch_bounds__(256) void scan_kernel(const int* __restrict__ counts,
                                                   int* __restrict__ row_ptr,
                                                   int* __restrict__ fill) {
  int t = threadIdx.x;
  const int CH = 40;
  int base = t * CH;
  int local[CH];
  int sum = 0;
#pragma unroll
  for (int i = 0; i < CH; i++) {
    int idx = base + i;
    int v = (idx < NNODES) ? counts[idx] : 0;
    local[i] = sum;
    sum += v;
  }
  __shared__ int ssum[256];
  ssum[t] = sum;
  __syncthreads();
  for (int off = 1; off < 256; off <<= 1) {
    int add = (t >= off) ? ssum[t - off] : 0;
    __syncthreads();
    ssum[t] += add;
    __syncthreads();
  }
  int excl = ssum[t] - sum;
#pragma unroll
  for (int i = 0; i < CH; i++) {
    int idx = base + i;
    if (idx < NNODES) {
      int v = excl + local[i];
      row_ptr[idx] = v;
      fill[idx] = v;
    }
  }
  if (t == 255) row_ptr[NNODES] = ssum[255];
}

__global__ void scatter_kernel(const int* __restrict__ ei, int* __restrict__ fill,
                               int* __restrict__ col_idx) {
  int e = blockIdx.x * blockDim.x + threadIdx.x;
  if (e >= ETOT) return;
  int s, d;
  if (e < NEDGE_IN) { s = ei[e]; d = ei[NEDGE_IN + e]; } else { s = d = e - NEDGE_IN; }
  int pos = atomicAdd(&fill[d], 1);
  col_idx[pos] = s;
}

// ---------------- split fp32 -> hi/lo bf16 (truncation split) ----------------
__global__ __launch_bounds__(256) void split_bf16_kernel(const float* __restrict__ z,
                                                         unsigned short* __restrict__ hi,
                                                         unsigned short* __restrict__ lo) {
  int i = blockIdx.x * 256 + threadIdx.x;
  if (i >= NNODES * FDIM) return;
  float v = z[i];
  unsigned u = __float_as_uint(v);
  unsigned hu = u & 0xffff0000u;
  float r = v - __uint_as_float(hu);
  hi[i] = (unsigned short)(u >> 16);
  lo[i] = (unsigned short)(__float_as_uint(r) >> 16);
}

// ---------------- BT prep: BT[f, h*256+k] = 0.25*W[k, h*256+f], split hi/lo ----------------
__global__ __launch_bounds__(256) void prep_bt_kernel(const float* __restrict__ W,
                                                      unsigned short* __restrict__ btHi,
                                                      unsigned short* __restrict__ btLo) {
  __shared__ float tile[32][33];
  int t = threadIdx.x;
  int tx = t & 31, ty = t >> 5;  // ty 0..7
  int f0 = blockIdx.x * 32, k0 = blockIdx.y * 32, h = blockIdx.z;
#pragma unroll
  for (int i = 0; i < 4; i++) {
    int kr = ty + 8 * i;
    tile[kr][tx] = W[(size_t)(k0 + kr) * 1024 + h * 256 + f0 + tx];
  }
  __syncthreads();
#pragma unroll
  for (int i = 0; i < 4; i++) {
    int fr = ty + 8 * i;
    float v = 0.25f * tile[tx][fr];
    unsigned u = __float_as_uint(v);
    float r = v - __uint_as_float(u & 0xffff0000u);
    size_t o = (size_t)(f0 + fr) * 1024 + h * 256 + k0 + tx;
    btHi[o] = (unsigned short)(u >> 16);
    btLo[o] = (unsigned short)(__float_as_uint(r) >> 16);
  }
}

// ---------------- Wa prep: Was/Wad[k,h] = sum_f W[k, h*256+f] * a[h,f] ----------------
__global__ __launch_bounds__(256) void prep_wa_kernel(const float* __restrict__ W,
                                                      const float* __restrict__ a_src,
                                                      const float* __restrict__ a_dst,
                                                      float* __restrict__ Was,
                                                      float* __restrict__ Wad) {
  int k = blockIdx.x, t = threadIdx.x;
  float ps[4], pd[4];
#pragma unroll
  for (int hd = 0; hd < 4; hd++) {
    float w = W[(size_t)k * 1024 + hd * 256 + t];
    ps[hd] = w * a_src[hd * 256 + t];
    pd[hd] = w * a_dst[hd * 256 + t];
  }
  __shared__ float red[8][4];
  int lane = t & 63, wv = t >> 6;
#pragma unroll
  for (int q = 0; q < 8; q++) {
    float v = (q < 4) ? ps[q] : pd[q - 4];
#pragma unroll
    for (int off = 32; off > 0; off >>= 1) v += __shfl_down(v, off, 64);
    if (lane == 0) red[q][wv] = v;
  }
  __syncthreads();
  if (t < 8) {
    float v = red[t][0] + red[t][1] + red[t][2] + red[t][3];
    if (t < 4) Was[k * 4 + t] = v;
    else Wad[k * 4 + (t - 4)] = v;
  }
}

// ---------------- al_s/al_d[n,h] = X[n,:] @ Was/Wad ----------------
__global__ __launch_bounds__(256) void al_kernel(const float* __restrict__ X,
                                                 const float* __restrict__ Was,
                                                 const float* __restrict__ Wad,
                                                 float* __restrict__ al_s,
                                                 float* __restrict__ al_d) {
  int n = blockIdx.x, t = threadIdx.x;
  float x = X[(size_t)n * 256 + t];
  float4 ws = *reinterpret_cast<const float4*>(Was + t * 4);
  float4 wd = *reinterpret_cast<const float4*>(Wad + t * 4);
  float ps[4] = {x * ws.x, x * ws.y, x * ws.z, x * ws.w};
  float pd[4] = {x * wd.x, x * wd.y, x * wd.z, x * wd.w};
  __shared__ float red[8][4];
  int lane = t & 63, wv = t >> 6;
#pragma unroll
  for (int q = 0; q < 8; q++) {
    float v = (q < 4) ? ps[q] : pd[q - 4];
#pragma unroll
    for (int off = 32; off > 0; off >>= 1) v += __shfl_down(v, off, 64);
    if (lane == 0) red[q][wv] = v;
  }
  __syncthreads();
  if (t < 8) {
    float v = red[t][0] + red[t][1] + red[t][2] + red[t][3];
    if (t < 4) al_s[n * 4 + t] = v;
    else al_d[n * 4 + (t - 4)] = v;
  }
}

// ---------------- single-pass softmax+gather: one wave per node ----------------
// alpha = ex/sum(ex) with ex = exp(leaky(logit)) (no max-shift; logits ~N(0,1),
// clamp at 60 for inf-safety). acc accumulates ex-weighted x; scaled by 1/sum at end.
__global__ __launch_bounds__(256) void gat_gather_kernel(
    const unsigned short* __restrict__ xhi, const float* __restrict__ al_s,
    const float* __restrict__ al_d, const int* __restrict__ row_ptr,
    const int* __restrict__ col_idx,
    unsigned short* __restrict__ aggHi, unsigned short* __restrict__ aggLo) {
  int t = threadIdx.x;
  int lane = t & 63, wv = t >> 6;
  int n = blockIdx.x * 4 + wv;
  int start = row_ptr[n], end = row_ptr[n + 1];
  float4 ald4 = *reinterpret_cast<const float4*>(al_d + n * 4);
  float ald[4] = {ald4.x, ald4.y, ald4.z, ald4.w};

  float acc[4][4] = {};
  float esum[4] = {0.f, 0.f, 0.f, 0.f};

  for (int c = start; c < end; c += 64) {
    int nch = min(64, end - c);
    int s = 0;
    float ex[4] = {0.f, 0.f, 0.f, 0.f};
    if (lane < nch) {
      s = col_idx[c + lane];
      float4 as4 = *reinterpret_cast<const float4*>(al_s + s * 4);
      float lv[4] = {as4.x + ald[0], as4.y + ald[1], as4.z + ald[2], as4.w + ald[3]};
#pragma unroll
      for (int h = 0; h < 4; h++) {
        float l = lv[h];
        l = (l > 0.f) ? l : 0.2f * l;
        l = fminf(l, 60.f);
        float e = __expf(l);
        ex[h] = e;
        esum[h] += e;
      }
    }
    for (int i = 0; i < nch; i++) {
      int si = __shfl(s, i, 64);
      float e0 = __shfl(ex[0], i, 64);
      float e1 = __shfl(ex[1], i, 64);
      float e2 = __shfl(ex[2], i, 64);
      float e3 = __shfl(ex[3], i, 64);
      ushort4 xv = *reinterpret_cast<const ushort4*>(xhi + (size_t)si * 256 + lane * 4);
      float xf0 = bf2f(xv.x), xf1 = bf2f(xv.y), xf2 = bf2f(xv.z), xf3 = bf2f(xv.w);
      acc[0][0] += xf0 * e0; acc[0][1] += xf1 * e0; acc[0][2] += xf2 * e0; acc[0][3] += xf3 * e0;
      acc[1][0] += xf0 * e1; acc[1][1] += xf1 * e1; acc[1][2] += xf2 * e1; acc[1][3] += xf3 * e1;
      acc[2][0] += xf0 * e2; acc[2][1] += xf1 * e2; acc[2][2] += xf2 * e2; acc[2][3] += xf3 * e2;
      acc[3][0] += xf0 * e3; acc[3][1] += xf1 * e3; acc[3][2] += xf2 * e3; acc[3][3] += xf3 * e3;
    }
  }

#pragma unroll
  for (int h = 0; h < 4; h++) {
#pragma unroll
    for (int m = 32; m > 0; m >>= 1) esum[h] += __shfl_xor(esum[h], m, 64);
  }

#pragma unroll
  for (int h = 0; h < 4; h++) {
    float inv = 1.f / (esum[h] + 1e-16f);
    ushort4 hv, lv;
    unsigned short* hp = (unsigned short*)&hv;
    unsigned short* lp = (unsigned short*)&lv;
#pragma unroll
    for (int j = 0; j < 4; j++) {
      float v = acc[h][j] * inv;
      unsigned u = __float_as_uint(v);
      float r = v - __uint_as_float(u & 0xffff0000u);
      hp[j] = (unsigned short)(u >> 16);
      lp[j] = (unsigned short)(__float_as_uint(r) >> 16);
    }
    size_t o = (size_t)n * 1024 + h * 256 + lane * 4;
    *reinterpret_cast<ushort4*>(aggHi + o) = hv;
    *reinterpret_cast<ushort4*>(aggLo + o) = lv;
  }
}

// ---------------- MFMA GEMM: out[N,256] = xagg[N,1024] @ BT^T + bias, act, split ----------------
#define AHI_OFF 0
#define ALO_OFF 16384
#define BHI_OFF 32768
#define BLO_OFF 49152

__global__ __launch_bounds__(256, 2) void gemm_out_kernel(
    const unsigned short* __restrict__ aggHi, const unsigned short* __restrict__ aggLo,
    const unsigned short* __restrict__ btHi, const unsigned short* __restrict__ btLo,
    const float* __restrict__ bias, float* __restrict__ outF,
    unsigned short* __restrict__ outHi, unsigned short* __restrict__ outLo, int act_tanh) {
  __shared__ __align__(16) char lds[65536];
  int t = threadIdx.x;
  int lane = t & 63, wv = t >> 6;
  int quad = lane >> 4, lr = lane & 15;
  int row0 = blockIdx.y * 128;
  int col0 = blockIdx.x * 128;
  int wm = (wv & 1) * 64, wn = (wv >> 1) * 64;

  floatx4 acc[4][4];
#pragma unroll
  for (int i = 0; i < 4; i++)
#pragma unroll
    for (int j = 0; j < 4; j++) acc[i][j] = (floatx4){0.f, 0.f, 0.f, 0.f};

  for (int ks = 0; ks < 16; ks++) {
#pragma unroll
    for (int mat = 0; mat < 4; mat++) {
      const unsigned short* src = (mat == 0) ? aggHi : (mat == 1) ? aggLo : (mat == 2) ? btHi : btLo;
      int rowbase = (mat < 2) ? row0 : col0;
      int maxrow = (mat < 2) ? (NNODES - 1) : 255;
      int ldsoff = mat * 16384;
#pragma unroll
      for (int it = 0; it < 4; it++) {
        int lin = ((wv * 4 + it) << 10) + lane * 16;
        int R = lin >> 7;
        int c = (lin >> 4) & 7;
        int g = c ^ (R & 7);
        int gr = rowbase + R;
        if (gr > maxrow) gr = maxrow;
        const char* gp = (const char*)src + (size_t)gr * 2048 + ks * 128 + g * 16;
        __builtin_amdgcn_global_load_lds(
            (const __attribute__((address_space(1))) void*)gp,
            (__attribute__((address_space(3))) void*)(lds + ldsoff + lin), 16, 0, 0);
      }
    }
    __syncthreads();

#pragma unroll
    for (int ksub = 0; ksub < 2; ksub++) {
      int g = ksub * 4 + quad;
      bf16x8 ah[4], al_[4], bh[4], bl[4];
#pragma unroll
      for (int mi = 0; mi < 4; mi++) {
        int m = wm + mi * 16 + lr;
        int off = m * 128 + ((g ^ (m & 7)) << 4);
        ah[mi] = *(const bf16x8*)(lds + AHI_OFF + off);
        al_[mi] = *(const bf16x8*)(lds + ALO_OFF + off);
      }
#pragma unroll
      for (int ni = 0; ni < 4; ni++) {
        int n = wn + ni * 16 + lr;
        int off = n * 128 + ((g ^ (n & 7)) << 4);
        bh[ni] = *(const bf16x8*)(lds + BHI_OFF + off);
        bl[ni] = *(const bf16x8*)(lds + BLO_OFF + off);
      }
#pragma unroll
      for (int mi = 0; mi < 4; mi++)
#pragma unroll
        for (int ni = 0; ni < 4; ni++) {
          acc[mi][ni] = __builtin_amdgcn_mfma_f32_16x16x32_bf16(ah[mi], bh[ni], acc[mi][ni], 0, 0, 0);
          acc[mi][ni] = __builtin_amdgcn_mfma_f32_16x16x32_bf16(ah[mi], bl[ni], acc[mi][ni], 0, 0, 0);
          acc[mi][ni] = __builtin_amdgcn_mfma_f32_16x16x32_bf16(al_[mi], bh[ni], acc[mi][ni], 0, 0, 0);
        }
    }
    __syncthreads();
  }

#pragma unroll
  for (int mi = 0; mi < 4; mi++) {
#pragma unroll
    for (int ni = 0; ni < 4; ni++) {
      int col = col0 + wn + ni * 16 + lr;
      float bv = bias[col];
#pragma unroll
      for (int r = 0; r < 4; r++) {
        int row = row0 + wm + mi * 16 + quad * 4 + r;
        if (row < NNODES) {
          float v = acc[mi][ni][r] + bv;
          v = act_tanh ? tanhf(v) : fmaxf(v, 0.f);
          size_t o = (size_t)row * 256 + col;
          outF[o] = v;
          unsigned u = __float_as_uint(v);
          float rr = v - __uint_as_float(u & 0xffff0000u);
          outHi[o] = (unsigned short)(u >> 16);
          outLo[o] = (unsigned short)(__float_as_uint(rr) >> 16);
        }
      }
    }
  }
}

// ---------------- adj = sigmoid(Z @ Z^T), symmetric: triangular grid + mirror ----------------
__global__ __launch_bounds__(256, 2) void zzt_mfma_kernel(
    const unsigned short* __restrict__ zhi, const unsigned short* __restrict__ zlo,
    float* __restrict__ out) {
  __shared__ __align__(16) char lds[65536];
  int t = threadIdx.x;
  int lane = t & 63, wv = t >> 6;
  int quad = lane >> 4, lr = lane & 15;

  // triangular decode: block p -> (bi, bj), bi <= bj
  int p = blockIdx.x;
  int bi = (int)((159.0f - sqrtf(159.0f * 159.0f - 8.0f * (float)p)) * 0.5f);
  if (bi < 0) bi = 0;
  if (bi > NT - 1) bi = NT - 1;
  while (bi * NT - bi * (bi - 1) / 2 > p) bi--;
  while ((bi + 1) * NT - (bi + 1) * bi / 2 <= p) bi++;
  int bj = bi + (p - (bi * NT - bi * (bi - 1) / 2));
  int row0 = bi * 128;
  int col0 = bj * 128;
  int wm = (wv & 1) * 64, wn = (wv >> 1) * 64;

  floatx4 acc[4][4];
#pragma unroll
  for (int i = 0; i < 4; i++)
#pragma unroll
    for (int j = 0; j < 4; j++) acc[i][j] = (floatx4){0.f, 0.f, 0.f, 0.f};

  for (int ks = 0; ks < 4; ks++) {
#pragma unroll
    for (int mat = 0; mat < 4; mat++) {
      const unsigned short* src = (mat == 0 || mat == 2) ? zhi : zlo;
      int rowbase = (mat < 2) ? row0 : col0;
      int ldsoff = mat * 16384;
#pragma unroll
      for (int it = 0; it < 4; it++) {
        int lin = ((wv * 4 + it) << 10) + lane * 16;
        int R = lin >> 7;
        int c = (lin >> 4) & 7;
        int g = c ^ (R & 7);
        int gr = rowbase + R;
        if (gr > NNODES - 1) gr = NNODES - 1;
        const char* gp = (const char*)src + (size_t)gr * 512 + ks * 128 + g * 16;
        __builtin_amdgcn_global_load_lds(
            (const __attribute__((address_space(1))) void*)gp,
            (__attribute__((address_space(3))) void*)(lds + ldsoff + lin), 16, 0, 0);
      }
    }
    __syncthreads();

#pragma unroll
    for (int ksub = 0; ksub < 2; ksub++) {
      int g = ksub * 4 + quad;
      bf16x8 ah[4], al_[4], bh[4], bl[4];
#pragma unroll
      for (int mi = 0; mi < 4; mi++) {
        int m = wm + mi * 16 + lr;
        int off = m * 128 + ((g ^ (m & 7)) << 4);
        ah[mi] = *(const bf16x8*)(lds + AHI_OFF + off);
        al_[mi] = *(const bf16x8*)(lds + ALO_OFF + off);
      }
#pragma unroll
      for (int ni = 0; ni < 4; ni++) {
        int n = wn + ni * 16 + lr;
        int off = n * 128 + ((g ^ (n & 7)) << 4);
        bh[ni] = *(const bf16x8*)(lds + BHI_OFF + off);
        bl[ni] = *(const bf16x8*)(lds + BLO_OFF + off);
      }
#pragma unroll
      for (int mi = 0; mi < 4; mi++)
#pragma unroll
        for (int ni = 0; ni < 4; ni++) {
          acc[mi][ni] = __builtin_amdgcn_mfma_f32_16x16x32_bf16(ah[mi], bh[ni], acc[mi][ni], 0, 0, 0);
          acc[mi][ni] = __builtin_amdgcn_mfma_f32_16x16x32_bf16(ah[mi], bl[ni], acc[mi][ni], 0, 0, 0);
          acc[mi][ni] = __builtin_amdgcn_mfma_f32_16x16x32_bf16(al_[mi], bh[ni], acc[mi][ni], 0, 0, 0);
        }
    }
    __syncthreads();
  }

  bool diag = (bi == bj);
#pragma unroll
  for (int mi = 0; mi < 4; mi++) {
#pragma unroll
    for (int ni = 0; ni < 4; ni++) {
      int col = col0 + wn + ni * 16 + lr;
      if (col >= NNODES) continue;
      float4 sv;
      sv.x = 1.f / (1.f + __expf(-acc[mi][ni][0]));
      sv.y = 1.f / (1.f + __expf(-acc[mi][ni][1]));
      sv.z = 1.f / (1.f + __expf(-acc[mi][ni][2]));
      sv.w = 1.f / (1.f + __expf(-acc[mi][ni][3]));
      float svv[4] = {sv.x, sv.y, sv.z, sv.w};
      int r0 = row0 + wm + mi * 16 + quad * 4;
#pragma unroll
      for (int r = 0; r < 4; r++) {
        if (r0 + r < NNODES) out[(size_t)(r0 + r) * NNODES + col] = svv[r];
      }
      if (!diag) {
        if (r0 + 3 < NNODES) {
          *reinterpret_cast<float4*>(&out[(size_t)col * NNODES + r0]) = sv;
        } else {
#pragma unroll
          for (int r = 0; r < 4; r++)
            if (r0 + r < NNODES) out[(size_t)col * NNODES + r0 + r] = svv[r];
        }
      }
    }
  }
}

extern "C" void kernel_launch(void* const* d_in, const int* in_sizes, int n_in,
                              void* d_out, int out_size, void* d_ws, size_t ws_size,
                              hipStream_t stream) {
  const float* x = (const float*)d_in[0];
  const int* ei = (const int*)d_in[1];
  const float* W[4]  = {(const float*)d_in[2], (const float*)d_in[6], (const float*)d_in[10], (const float*)d_in[14]};
  const float* as[4] = {(const float*)d_in[3], (const float*)d_in[7], (const float*)d_in[11], (const float*)d_in[15]};
  const float* ad[4] = {(const float*)d_in[4], (const float*)d_in[8], (const float*)d_in[12], (const float*)d_in[16]};
  const float* bs[4] = {(const float*)d_in[5], (const float*)d_in[9], (const float*)d_in[13], (const float*)d_in[17]};

  char* ws = (char*)d_ws;
  size_t off = 0;
  auto alloc = [&](size_t bytes) -> void* {
    void* p = ws + off;
    off = (off + bytes + 255) & ~(size_t)255;
    return p;
  };
  unsigned short* aggHi = (unsigned short*)alloc(sizeof(unsigned short) * (size_t)NNODES * 1024);
  unsigned short* aggLo = (unsigned short*)alloc(sizeof(unsigned short) * (size_t)NNODES * 1024);
  unsigned short* shi   = (unsigned short*)alloc(sizeof(unsigned short) * (size_t)NNODES * FDIM);
  unsigned short* slo   = (unsigned short*)alloc(sizeof(unsigned short) * (size_t)NNODES * FDIM);
  unsigned short* btHi  = (unsigned short*)alloc(sizeof(unsigned short) * 256 * 1024);
  unsigned short* btLo  = (unsigned short*)alloc(sizeof(unsigned short) * 256 * 1024);
  float* xF    = (float*)alloc(sizeof(float) * (size_t)NNODES * FDIM);
  float* al_s  = (float*)alloc(sizeof(float) * NNODES * 4);
  float* al_d  = (float*)alloc(sizeof(float) * NNODES * 4);
  float* Was   = (float*)alloc(sizeof(float) * 256 * 4);
  float* Wad   = (float*)alloc(sizeof(float) * 256 * 4);
  int* counts  = (int*)alloc(sizeof(int) * NNODES);
  int* row_ptr = (int*)alloc(sizeof(int) * (NNODES + 1));
  int* fill    = (int*)alloc(sizeof(int) * NNODES);
  int* col_idx = (int*)alloc(sizeof(int) * ETOT);

  hipMemsetAsync(counts, 0, sizeof(int) * NNODES, stream);
  int eblocks = (ETOT + 255) / 256;
  count_deg_kernel<<<eblocks, 256, 0, stream>>>(ei, counts);
  scan_kernel<<<1, 256, 0, stream>>>(counts, row_ptr, fill);
  scatter_kernel<<<eblocks, 256, 0, stream>>>(ei, fill, col_idx);
  split_bf16_kernel<<<(NNODES * FDIM + 255) / 256, 256, 0, stream>>>(x, shi, slo);

  float* z = (float*)d_out + (size_t)NNODES * NNODES;
  const float* xin = x;
  for (int l = 0; l < 4; l++) {
    prep_bt_kernel<<<dim3(8, 8, 4), 256, 0, stream>>>(W[l], btHi, btLo);
    prep_wa_kernel<<<256, 256, 0, stream>>>(W[l], as[l], ad[l], Was, Wad);
    al_kernel<<<NNODES, 256, 0, stream>>>(xin, Was, Wad, al_s, al_d);
    gat_gather_kernel<<<NNODES / 4, 256, 0, stream>>>(shi, al_s, al_d, row_ptr, col_idx,
                                                      aggHi, aggLo);
    float* outF = (l == 3) ? z : xF;
    gemm_out_kernel<<<dim3(2, 79), 256, 0, stream>>>(aggHi, aggLo, btHi, btLo, bs[l],
                                                     outF, shi, slo, l == 3 ? 1 : 0);
    xin = xF;
  }
  zzt_mfma_kernel<<<NT * (NT + 1) / 2, 256, 0, stream>>>(shi, slo, (float*)d_out);
}

// Round 6
// 996.431 us; speedup vs baseline: 2.3645x; 1.0647x over previous
//
#include <hip/hip_runtime.h>
#include <hip/hip_bf16.h>

#define NNODES 10000
#define NEDGE_IN 320000
#define ETOT (NEDGE_IN + NNODES)
#define FDIM 256
#define NT 79  // 128-tiles covering 10000

typedef float floatx4 __attribute__((ext_vector_type(4)));
typedef __bf16 bf16x8 __attribute__((ext_vector_type(8)));

__device__ __forceinline__ float bf2f(unsigned short u) {
  return __uint_as_float((unsigned)u << 16);
}

// ---------------- CSR build (dst-grouped incoming edge lists) ----------------
__global__ void count_deg_kernel(const int* __restrict__ ei, int* __restrict__ counts) {
  int e = blockIdx.x * blockDim.x + threadIdx.x;
  if (e >= ETOT) return;
  int d = (e < NEDGE_IN) ? ei[NEDGE_IN + e] : (e - NEDGE_IN);
  atomicAdd(&counts[d], 1);
}

__global__ __launch_bounds__(256) void scan_kernel(const int* __restrict__ counts,
                                                   int* __restrict__ row_ptr,
                                                   int* __restrict__ fill) {
  int t = threadIdx.x;
  const int CH = 40;
  int base = t * CH;
  int local[CH];
  int sum = 0;
#pragma unroll
  for (int i = 0; i < CH; i++) {
    int idx = base + i;
    int v = (idx < NNODES) ? counts[idx] : 0;
    local[i] = sum;
    sum += v;
  }
  __shared__ int ssum[256];
  ssum[t] = sum;
  __syncthreads();
  for (int off = 1; off < 256; off <<= 1) {
    int add = (t >= off) ? ssum[t - off] : 0;
    __syncthreads();
    ssum[t] += add;
    __syncthreads();
  }
  int excl = ssum[t] - sum;
#pragma unroll
  for (int i = 0; i < CH; i++) {
    int idx = base + i;
    if (idx < NNODES) {
      int v = excl + local[i];
      row_ptr[idx] = v;
      fill[idx] = v;
    }
  }
  if (t == 255) row_ptr[NNODES] = ssum[255];
}

__global__ void scatter_kernel(const int* __restrict__ ei, int* __restrict__ fill,
                               int* __restrict__ col_idx) {
  int e = blockIdx.x * blockDim.x + threadIdx.x;
  if (e >= ETOT) return;
  int s, d;
  if (e < NEDGE_IN) { s = ei[e]; d = ei[NEDGE_IN + e]; } else { s = d = e - NEDGE_IN; }
  int pos = atomicAdd(&fill[d], 1);
  col_idx[pos] = s;
}

// ---------------- split fp32 -> hi/lo bf16 (truncation split) ----------------
__global__ __launch_bounds__(256) void split_bf16_kernel(const float* __restrict__ z,
                                                         unsigned short* __restrict__ hi,
                                                         unsigned short* __restrict__ lo) {
  int i = blockIdx.x * 256 + threadIdx.x;
  if (i >= NNODES * FDIM) return;
  float v = z[i];
  unsigned u = __float_as_uint(v);
  unsigned hu = u & 0xffff0000u;
  float r = v - __uint_as_float(hu);
  hi[i] = (unsigned short)(u >> 16);
  lo[i] = (unsigned short)(__float_as_uint(r) >> 16);
}

// ---------------- BT prep: BT[f, h*256+k] = 0.25*W[k, h*256+f], split hi/lo ----------------
__global__ __launch_bounds__(256) void prep_bt_kernel(const float* __restrict__ W,
                                                      unsigned short* __restrict__ btHi,
                                                      unsigned short* __restrict__ btLo) {
  __shared__ float tile[32][33];
  int t = threadIdx.x;
  int tx = t & 31, ty = t >> 5;  // ty 0..7
  int f0 = blockIdx.x * 32, k0 = blockIdx.y * 32, h = blockIdx.z;
#pragma unroll
  for (int i = 0; i < 4; i++) {
    int kr = ty + 8 * i;
    tile[kr][tx] = W[(size_t)(k0 + kr) * 1024 + h * 256 + f0 + tx];
  }
  __syncthreads();
#pragma unroll
  for (int i = 0; i < 4; i++) {
    int fr = ty + 8 * i;
    float v = 0.25f * tile[tx][fr];
    unsigned u = __float_as_uint(v);
    float r = v - __uint_as_float(u & 0xffff0000u);
    size_t o = (size_t)(f0 + fr) * 1024 + h * 256 + k0 + tx;
    btHi[o] = (unsigned short)(u >> 16);
    btLo[o] = (unsigned short)(__float_as_uint(r) >> 16);
  }
}

// ---------------- Wa prep: Was/Wad[k,h] = sum_f W[k, h*256+f] * a[h,f] ----------------
__global__ __launch_bounds__(256) void prep_wa_kernel(const float* __restrict__ W,
                                                      const float* __restrict__ a_src,
                                                      const float* __restrict__ a_dst,
                                                      float* __restrict__ Was,
                                                      float* __restrict__ Wad) {
  int k = blockIdx.x, t = threadIdx.x;
  float ps[4], pd[4];
#pragma unroll
  for (int hd = 0; hd < 4; hd++) {
    float w = W[(size_t)k * 1024 + hd * 256 + t];
    ps[hd] = w * a_src[hd * 256 + t];
    pd[hd] = w * a_dst[hd * 256 + t];
  }
  __shared__ float red[8][4];
  int lane = t & 63, wv = t >> 6;
#pragma unroll
  for (int q = 0; q < 8; q++) {
    float v = (q < 4) ? ps[q] : pd[q - 4];
#pragma unroll
    for (int off = 32; off > 0; off >>= 1) v += __shfl_down(v, off, 64);
    if (lane == 0) red[q][wv] = v;
  }
  __syncthreads();
  if (t < 8) {
    float v = red[t][0] + red[t][1] + red[t][2] + red[t][3];
    if (t < 4) Was[k * 4 + t] = v;
    else Wad[k * 4 + (t - 4)] = v;
  }
}

// ---------------- al_s/al_d[n,h] = X[n,:] @ Was/Wad (X = hi+lo reconstruct) ----------------
__global__ __launch_bounds__(256) void al_kernel(const unsigned short* __restrict__ xhi,
                                                 const unsigned short* __restrict__ xlo,
                                                 const float* __restrict__ Was,
                                                 const float* __restrict__ Wad,
                                                 float* __restrict__ al_s,
                                                 float* __restrict__ al_d) {
  int n = blockIdx.x, t = threadIdx.x;
  float x = bf2f(xhi[(size_t)n * 256 + t]) + bf2f(xlo[(size_t)n * 256 + t]);
  float4 ws = *reinterpret_cast<const float4*>(Was + t * 4);
  float4 wd = *reinterpret_cast<const float4*>(Wad + t * 4);
  float ps[4] = {x * ws.x, x * ws.y, x * ws.z, x * ws.w};
  float pd[4] = {x * wd.x, x * wd.y, x * wd.z, x * wd.w};
  __shared__ float red[8][4];
  int lane = t & 63, wv = t >> 6;
#pragma unroll
  for (int q = 0; q < 8; q++) {
    float v = (q < 4) ? ps[q] : pd[q - 4];
#pragma unroll
    for (int off = 32; off > 0; off >>= 1) v += __shfl_down(v, off, 64);
    if (lane == 0) red[q][wv] = v;
  }
  __syncthreads();
  if (t < 8) {
    float v = red[t][0] + red[t][1] + red[t][2] + red[t][3];
    if (t < 4) al_s[n * 4 + t] = v;
    else al_d[n * 4 + (t - 4)] = v;
  }
}

// ---------------- single-pass softmax+gather, wave-per-node, LDS chunk cache ----------------
#define ACC4(xv, e)                                                              \
  {                                                                              \
    float f0 = bf2f(xv.x), f1 = bf2f(xv.y), f2 = bf2f(xv.z), f3 = bf2f(xv.w);    \
    acc[0][0] += f0 * e.x; acc[0][1] += f1 * e.x; acc[0][2] += f2 * e.x; acc[0][3] += f3 * e.x; \
    acc[1][0] += f0 * e.y; acc[1][1] += f1 * e.y; acc[1][2] += f2 * e.y; acc[1][3] += f3 * e.y; \
    acc[2][0] += f0 * e.z; acc[2][1] += f1 * e.z; acc[2][2] += f2 * e.z; acc[2][3] += f3 * e.z; \
    acc[3][0] += f0 * e.w; acc[3][1] += f1 * e.w; acc[3][2] += f2 * e.w; acc[3][3] += f3 * e.w; \
  }

__global__ __launch_bounds__(256) void gat_gather_kernel(
    const unsigned short* __restrict__ xhi, const float* __restrict__ al_s,
    const float* __restrict__ al_d, const int* __restrict__ row_ptr,
    const int* __restrict__ col_idx,
    unsigned short* __restrict__ aggHi, unsigned short* __restrict__ aggLo) {
  __shared__ int sS[4][64];
  __shared__ float4 sE[4][64];
  int t = threadIdx.x;
  int lane = t & 63, wv = t >> 6;
  int n = blockIdx.x * 4 + wv;
  int start = row_ptr[n], end = row_ptr[n + 1];
  float4 ald4 = *reinterpret_cast<const float4*>(al_d + n * 4);
  float ald[4] = {ald4.x, ald4.y, ald4.z, ald4.w};

  float acc[4][4] = {};
  float esum[4] = {0.f, 0.f, 0.f, 0.f};

  for (int c = start; c < end; c += 64) {
    int nch = min(64, end - c);
    int s = 0;
    float ex[4] = {0.f, 0.f, 0.f, 0.f};
    if (lane < nch) {
      s = col_idx[c + lane];
      float4 as4 = *reinterpret_cast<const float4*>(al_s + s * 4);
      float lv[4] = {as4.x + ald[0], as4.y + ald[1], as4.z + ald[2], as4.w + ald[3]};
#pragma unroll
      for (int h = 0; h < 4; h++) {
        float l = lv[h];
        l = (l > 0.f) ? l : 0.2f * l;
        l = fminf(l, 60.f);
        float e = __expf(l);
        ex[h] = e;
        esum[h] += e;
      }
    }
    sS[wv][lane] = s;
    sE[wv][lane] = make_float4(ex[0], ex[1], ex[2], ex[3]);
    __asm__ __volatile__("" ::: "memory");  // per-wave LDS ops are in-order; pin compiler order
    int i = 0;
    for (; i + 4 <= nch; i += 4) {
      int s0 = sS[wv][i], s1 = sS[wv][i + 1], s2 = sS[wv][i + 2], s3 = sS[wv][i + 3];
      float4 e0 = sE[wv][i], e1 = sE[wv][i + 1], e2 = sE[wv][i + 2], e3 = sE[wv][i + 3];
      ushort4 x0 = *reinterpret_cast<const ushort4*>(xhi + (size_t)s0 * 256 + lane * 4);
      ushort4 x1 = *reinterpret_cast<const ushort4*>(xhi + (size_t)s1 * 256 + lane * 4);
      ushort4 x2 = *reinterpret_cast<const ushort4*>(xhi + (size_t)s2 * 256 + lane * 4);
      ushort4 x3 = *reinterpret_cast<const ushort4*>(xhi + (size_t)s3 * 256 + lane * 4);
      ACC4(x0, e0);
      ACC4(x1, e1);
      ACC4(x2, e2);
      ACC4(x3, e3);
    }
    for (; i < nch; i++) {
      int s0 = sS[wv][i];
      float4 e0 = sE[wv][i];
      ushort4 x0 = *reinterpret_cast<const ushort4*>(xhi + (size_t)s0 * 256 + lane * 4);
      ACC4(x0, e0);
    }
    __asm__ __volatile__("" ::: "memory");
  }

#pragma unroll
  for (int h = 0; h < 4; h++) {
#pragma unroll
    for (int m = 32; m > 0; m >>= 1) esum[h] += __shfl_xor(esum[h], m, 64);
  }

#pragma unroll
  for (int h = 0; h < 4; h++) {
    float inv = 1.f / (esum[h] + 1e-16f);
    ushort4 hv, lv;
    unsigned short* hp = (unsigned short*)&hv;
    unsigned short* lp = (unsigned short*)&lv;
#pragma unroll
    for (int j = 0; j < 4; j++) {
      float v = acc[h][j] * inv;
      unsigned u = __float_as_uint(v);
      float r = v - __uint_as_float(u & 0xffff0000u);
      hp[j] = (unsigned short)(u >> 16);
      lp[j] = (unsigned short)(__float_as_uint(r) >> 16);
    }
    size_t o = (size_t)n * 1024 + h * 256 + lane * 4;
    *reinterpret_cast<ushort4*>(aggHi + o) = hv;
    *reinterpret_cast<ushort4*>(aggLo + o) = lv;
  }
}

// ---------------- MFMA GEMM: out[N,256] = xagg[N,1024] @ BT^T + bias, act, split ----------------
#define AHI_OFF 0
#define ALO_OFF 16384
#define BHI_OFF 32768
#define BLO_OFF 49152

__global__ __launch_bounds__(256, 2) void gemm_out_kernel(
    const unsigned short* __restrict__ aggHi, const unsigned short* __restrict__ aggLo,
    const unsigned short* __restrict__ btHi, const unsigned short* __restrict__ btLo,
    const float* __restrict__ bias, float* __restrict__ outF,
    unsigned short* __restrict__ outHi, unsigned short* __restrict__ outLo, int act_tanh) {
  __shared__ __align__(16) char lds[65536];
  int t = threadIdx.x;
  int lane = t & 63, wv = t >> 6;
  int quad = lane >> 4, lr = lane & 15;
  int row0 = blockIdx.y * 128;
  int col0 = blockIdx.x * 128;
  int wm = (wv & 1) * 64, wn = (wv >> 1) * 64;

  floatx4 acc[4][4];
#pragma unroll
  for (int i = 0; i < 4; i++)
#pragma unroll
    for (int j = 0; j < 4; j++) acc[i][j] = (floatx4){0.f, 0.f, 0.f, 0.f};

  for (int ks = 0; ks < 16; ks++) {
#pragma unroll
    for (int mat = 0; mat < 4; mat++) {
      const unsigned short* src = (mat == 0) ? aggHi : (mat == 1) ? aggLo : (mat == 2) ? btHi : btLo;
      int rowbase = (mat < 2) ? row0 : col0;
      int maxrow = (mat < 2) ? (NNODES - 1) : 255;
      int ldsoff = mat * 16384;
#pragma unroll
      for (int it = 0; it < 4; it++) {
        int lin = ((wv * 4 + it) << 10) + lane * 16;
        int R = lin >> 7;
        int c = (lin >> 4) & 7;
        int g = c ^ (R & 7);
        int gr = rowbase + R;
        if (gr > maxrow) gr = maxrow;
        const char* gp = (const char*)src + (size_t)gr * 2048 + ks * 128 + g * 16;
        __builtin_amdgcn_global_load_lds(
            (const __attribute__((address_space(1))) void*)gp,
            (__attribute__((address_space(3))) void*)(lds + ldsoff + lin), 16, 0, 0);
      }
    }
    __syncthreads();

#pragma unroll
    for (int ksub = 0; ksub < 2; ksub++) {
      int g = ksub * 4 + quad;
      bf16x8 ah[4], al_[4], bh[4], bl[4];
#pragma unroll
      for (int mi = 0; mi < 4; mi++) {
        int m = wm + mi * 16 + lr;
        int off = m * 128 + ((g ^ (m & 7)) << 4);
        ah[mi] = *(const bf16x8*)(lds + AHI_OFF + off);
        al_[mi] = *(const bf16x8*)(lds + ALO_OFF + off);
      }
#pragma unroll
      for (int ni = 0; ni < 4; ni++) {
        int n = wn + ni * 16 + lr;
        int off = n * 128 + ((g ^ (n & 7)) << 4);
        bh[ni] = *(const bf16x8*)(lds + BHI_OFF + off);
        bl[ni] = *(const bf16x8*)(lds + BLO_OFF + off);
      }
#pragma unroll
      for (int mi = 0; mi < 4; mi++)
#pragma unroll
        for (int ni = 0; ni < 4; ni++) {
          acc[mi][ni] = __builtin_amdgcn_mfma_f32_16x16x32_bf16(ah[mi], bh[ni], acc[mi][ni], 0, 0, 0);
          acc[mi][ni] = __builtin_amdgcn_mfma_f32_16x16x32_bf16(ah[mi], bl[ni], acc[mi][ni], 0, 0, 0);
          acc[mi][ni] = __builtin_amdgcn_mfma_f32_16x16x32_bf16(al_[mi], bh[ni], acc[mi][ni], 0, 0, 0);
        }
    }
    __syncthreads();
  }

#pragma unroll
  for (int mi = 0; mi < 4; mi++) {
#pragma unroll
    for (int ni = 0; ni < 4; ni++) {
      int col = col0 + wn + ni * 16 + lr;
      float bv = bias[col];
#pragma unroll
      for (int r = 0; r < 4; r++) {
        int row = row0 + wm + mi * 16 + quad * 4 + r;
        if (row < NNODES) {
          float v = acc[mi][ni][r] + bv;
          v = act_tanh ? tanhf(v) : fmaxf(v, 0.f);
          size_t o = (size_t)row * 256 + col;
          if (outF) outF[o] = v;
          unsigned u = __float_as_uint(v);
          float rr = v - __uint_as_float(u & 0xffff0000u);
          outHi[o] = (unsigned short)(u >> 16);
          outLo[o] = (unsigned short)(__float_as_uint(rr) >> 16);
        }
      }
    }
  }
}

// ---------------- adj = sigmoid(Z @ Z^T), triangular grid, LDS-transposed mirror ----------------
__global__ __launch_bounds__(256, 2) void zzt_mfma_kernel(
    const unsigned short* __restrict__ zhi, const unsigned short* __restrict__ zlo,
    float* __restrict__ out) {
  __shared__ __align__(16) char lds[65536];
  int t = threadIdx.x;
  int lane = t & 63, wv = t >> 6;
  int quad = lane >> 4, lr = lane & 15;

  // triangular decode: block p -> (bi, bj), bi <= bj
  int p = blockIdx.x;
  int bi = (int)((159.0f - sqrtf(159.0f * 159.0f - 8.0f * (float)p)) * 0.5f);
  if (bi < 0) bi = 0;
  if (bi > NT - 1) bi = NT - 1;
  while (bi * NT - bi * (bi - 1) / 2 > p) bi--;
  while ((bi + 1) * NT - (bi + 1) * bi / 2 <= p) bi++;
  int bj = bi + (p - (bi * NT - bi * (bi - 1) / 2));
  int row0 = bi * 128;
  int col0 = bj * 128;
  int wm = (wv & 1) * 64, wn = (wv >> 1) * 64;

  floatx4 acc[4][4];
#pragma unroll
  for (int i = 0; i < 4; i++)
#pragma unroll
    for (int j = 0; j < 4; j++) acc[i][j] = (floatx4){0.f, 0.f, 0.f, 0.f};

  for (int ks = 0; ks < 4; ks++) {
#pragma unroll
    for (int mat = 0; mat < 4; mat++) {
      const unsigned short* src = (mat == 0 || mat == 2) ? zhi : zlo;
      int rowbase = (mat < 2) ? row0 : col0;
      int ldsoff = mat * 16384;
#pragma unroll
      for (int it = 0; it < 4; it++) {
        int lin = ((wv * 4 + it) << 10) + lane * 16;
        int R = lin >> 7;
        int c = (lin >> 4) & 7;
        int g = c ^ (R & 7);
        int gr = rowbase + R;
        if (gr > NNODES - 1) gr = NNODES - 1;
        const char* gp = (const char*)src + (size_t)gr * 512 + ks * 128 + g * 16;
        __builtin_amdgcn_global_load_lds(
            (const __attribute__((address_space(1))) void*)gp,
            (__attribute__((address_space(3))) void*)(lds + ldsoff + lin), 16, 0, 0);
      }
    }
    __syncthreads();

#pragma unroll
    for (int ksub = 0; ksub < 2; ksub++) {
      int g = ksub * 4 + quad;
      bf16x8 ah[4], al_[4], bh[4], bl[4];
#pragma unroll
      for (int mi = 0; mi < 4; mi++) {
        int m = wm + mi * 16 + lr;
        int off = m * 128 + ((g ^ (m & 7)) << 4);
        ah[mi] = *(const bf16x8*)(lds + AHI_OFF + off);
        al_[mi] = *(const bf16x8*)(lds + ALO_OFF + off);
      }
#pragma unroll
      for (int ni = 0; ni < 4; ni++) {
        int n = wn + ni * 16 + lr;
        int off = n * 128 + ((g ^ (n & 7)) << 4);
        bh[ni] = *(const bf16x8*)(lds + BHI_OFF + off);
        bl[ni] = *(const bf16x8*)(lds + BLO_OFF + off);
      }
#pragma unroll
      for (int mi = 0; mi < 4; mi++)
#pragma unroll
        for (int ni = 0; ni < 4; ni++) {
          acc[mi][ni] = __builtin_amdgcn_mfma_f32_16x16x32_bf16(ah[mi], bh[ni], acc[mi][ni], 0, 0, 0);
          acc[mi][ni] = __builtin_amdgcn_mfma_f32_16x16x32_bf16(ah[mi], bl[ni], acc[mi][ni], 0, 0, 0);
          acc[mi][ni] = __builtin_amdgcn_mfma_f32_16x16x32_bf16(al_[mi], bh[ni], acc[mi][ni], 0, 0, 0);
        }
    }
    __syncthreads();
  }

  bool diag = (bi == bj);
  float4* ltile = (float4*)lds;  // 128 cols x 32 float4-rows, skewed: idx = c*32 + ((rq+c)&31)

#pragma unroll
  for (int mi = 0; mi < 4; mi++) {
#pragma unroll
    for (int ni = 0; ni < 4; ni++) {
      int cl = wn + ni * 16 + lr;  // local col
      int col = col0 + cl;
      float4 sv;
      sv.x = 1.f / (1.f + __expf(-acc[mi][ni][0]));
      sv.y = 1.f / (1.f + __expf(-acc[mi][ni][1]));
      sv.z = 1.f / (1.f + __expf(-acc[mi][ni][2]));
      sv.w = 1.f / (1.f + __expf(-acc[mi][ni][3]));
      float svv[4] = {sv.x, sv.y, sv.z, sv.w};
      int rl0 = wm + mi * 16 + quad * 4;  // local row base (multiple of 4)
      if (col < NNODES) {
#pragma unroll
        for (int r = 0; r < 4; r++) {
          int row = row0 + rl0 + r;
          if (row < NNODES) out[(size_t)row * NNODES + col] = svv[r];
        }
      }
      if (!diag) {
        int rq = rl0 >> 2;
        ltile[cl * 32 + ((rq + cl) & 31)] = sv;
      }
    }
  }

  if (!diag) {
    __syncthreads();
    // mirror: wave wv covers cols [wv*32, wv*32+32), 2 cols per iter, coalesced rows
#pragma unroll
    for (int it = 0; it < 16; it++) {
      int cl = wv * 32 + it * 2 + (lane >> 5);
      int rq = lane & 31;
      int col = col0 + cl;
      if (col < NNODES) {
        float4 v = ltile[cl * 32 + ((rq + cl) & 31)];
        *reinterpret_cast<float4*>(&out[(size_t)col * NNODES + row0 + 4 * rq]) = v;
      }
    }
  }
}

extern "C" void kernel_launch(void* const* d_in, const int* in_sizes, int n_in,
                              void* d_out, int out_size, void* d_ws, size_t ws_size,
                              hipStream_t stream) {
  const float* x = (const float*)d_in[0];
  const int* ei = (const int*)d_in[1];
  const float* W[4]  = {(const float*)d_in[2], (const float*)d_in[6], (const float*)d_in[10], (const float*)d_in[14]};
  const float* as[4] = {(const float*)d_in[3], (const float*)d_in[7], (const float*)d_in[11], (const float*)d_in[15]};
  const float* ad[4] = {(const float*)d_in[4], (const float*)d_in[8], (const float*)d_in[12], (const float*)d_in[16]};
  const float* bs[4] = {(const float*)d_in[5], (const float*)d_in[9], (const float*)d_in[13], (const float*)d_in[17]};

  char* ws = (char*)d_ws;
  size_t off = 0;
  auto alloc = [&](size_t bytes) -> void* {
    void* p = ws + off;
    off = (off + bytes + 255) & ~(size_t)255;
    return p;
  };
  unsigned short* aggHi = (unsigned short*)alloc(sizeof(unsigned short) * (size_t)NNODES * 1024);
  unsigned short* aggLo = (unsigned short*)alloc(sizeof(unsigned short) * (size_t)NNODES * 1024);
  unsigned short* shi   = (unsigned short*)alloc(sizeof(unsigned short) * (size_t)NNODES * FDIM);
  unsigned short* slo   = (unsigned short*)alloc(sizeof(unsigned short) * (size_t)NNODES * FDIM);
  unsigned short* btHi  = (unsigned short*)alloc(sizeof(unsigned short) * 256 * 1024);
  unsigned short* btLo  = (unsigned short*)alloc(sizeof(unsigned short) * 256 * 1024);
  float* al_s  = (float*)alloc(sizeof(float) * NNODES * 4);
  float* al_d  = (float*)alloc(sizeof(float) * NNODES * 4);
  float* Was   = (float*)alloc(sizeof(float) * 256 * 4);
  float* Wad   = (float*)alloc(sizeof(float) * 256 * 4);
  int* counts  = (int*)alloc(sizeof(int) * NNODES);
  int* row_ptr = (int*)alloc(sizeof(int) * (NNODES + 1));
  int* fill    = (int*)alloc(sizeof(int) * NNODES);
  int* col_idx = (int*)alloc(sizeof(int) * ETOT);

  hipMemsetAsync(counts, 0, sizeof(int) * NNODES, stream);
  int eblocks = (ETOT + 255) / 256;
  count_deg_kernel<<<eblocks, 256, 0, stream>>>(ei, counts);
  scan_kernel<<<1, 256, 0, stream>>>(counts, row_ptr, fill);
  scatter_kernel<<<eblocks, 256, 0, stream>>>(ei, fill, col_idx);
  split_bf16_kernel<<<(NNODES * FDIM + 255) / 256, 256, 0, stream>>>(x, shi, slo);

  float* z = (float*)d_out + (size_t)NNODES * NNODES;
  for (int l = 0; l < 4; l++) {
    prep_bt_kernel<<<dim3(8, 8, 4), 256, 0, stream>>>(W[l], btHi, btLo);
    prep_wa_kernel<<<256, 256, 0, stream>>>(W[l], as[l], ad[l], Was, Wad);
    al_kernel<<<NNODES, 256, 0, stream>>>(shi, slo, Was, Wad, al_s, al_d);
    gat_gather_kernel<<<NNODES / 4, 256, 0, stream>>>(shi, al_s, al_d, row_ptr, col_idx,
                                                      aggHi, aggLo);
    float* outF = (l == 3) ? z : (float*)nullptr;
    gemm_out_kernel<<<dim3(2, 79), 256, 0, stream>>>(aggHi, aggLo, btHi, btLo, bs[l],
                                                     outF, shi, slo, l == 3 ? 1 : 0);
  }
  zzt_mfma_kernel<<<NT * (NT + 1) / 2, 256, 0, stream>>>(shi, slo, (float*)d_out);
}